// Round 3
// baseline (334.850 us; speedup 1.0000x reference)
//
#include <hip/hip_runtime.h>

typedef unsigned short u16;
typedef u16 u16x4 __attribute__((ext_vector_type(4)));
typedef u16 u16x8 __attribute__((ext_vector_type(8)));
typedef __bf16 bf16x8 __attribute__((ext_vector_type(8)));
typedef float f32x16 __attribute__((ext_vector_type(16)));

static __device__ __forceinline__ u16 f2bf(float f) {
  unsigned u = __builtin_bit_cast(unsigned, f);
  u += 0x7fffu + ((u >> 16) & 1u);   // RNE; finite inputs
  return (u16)(u >> 16);
}
static __device__ __forceinline__ float bf2f(u16 h) {
  return __builtin_bit_cast(float, ((unsigned)h) << 16);
}

// async global->LDS, 16B/lane. LDS dest = wave-uniform base + lane*16.
static __device__ __forceinline__ void gload_lds16(const u16* g, u16* l) {
  u16* gn = const_cast<u16*>(g);
  __builtin_amdgcn_global_load_lds(
      (__attribute__((address_space(1))) unsigned int*)gn,
      (__attribute__((address_space(3))) unsigned int*)l,
      16, 0, 0);
}

__global__ __launch_bounds__(256)
void cvt_f32_bf16(const float* __restrict__ in, u16* __restrict__ out) {
  const int i = blockIdx.x * 256 + threadIdx.x;
  float4 f = ((const float4*)in)[i];
  u16x4 o = { f2bf(f.x), f2bf(f.y), f2bf(f.z), f2bf(f.w) };
  ((u16x4*)out)[i] = o;
}

__global__ __launch_bounds__(256)
void cvt_w3(const float* __restrict__ a, const float* __restrict__ b,
            const float* __restrict__ c, u16* __restrict__ out) {
  const int blk = blockIdx.x;       // 0..3071
  const int w = blk >> 10;
  const float* src = (w == 0) ? a : (w == 1) ? b : c;
  const int i = (blk & 1023) * 256 + threadIdx.x;
  float4 f = ((const float4*)src)[i];
  u16x4 o = { f2bf(f.x), f2bf(f.y), f2bf(f.z), f2bf(f.w) };
  ((u16x4*)(out + (size_t)w * 1048576ULL))[i] = o;
}

// ============================================================================
// 128x128 GEMM, C[m][n] = sum_k A[m][k]*B[n][k], k-contiguous inputs.
// mfma_f32_32x32x16_bf16; 4 waves (2x2), wave tile 64x64 = 2x2 of 32x32.
// ROUND-3 CHANGE (T3-minimum, m248v2/m230): BK 64->32, LDS double-buffered
// [2][128x32] A + B = 32 KiB total (same as round-0 -> same residency).
// Per tile: issue NEXT tile's 4 gloads at the TOP, compute CURRENT tile,
// then ONE __syncthreads() (its vmcnt(0) drains loads that had the whole
// compute section as leash — round-0 drained them with zero leash).
// Safety: reads of buf b complete (lgkm forced by MFMA uses) before the
// end-of-tile barrier; each wave's vmcnt covers its own stage instrs, and
// the barrier publishes them to all waves before consumption.
// LDS swizzle (4 chunks of 16B per row): pos p holds global chunk
// p ^ ((row>>1)&3) — 4-way conflict minimum (hidden at 2-phase, m252).
// A/B frag: [row=lane&31][k = ks*16 + (lane>>5)*8 + j]
// C/D frag (m74/m101): col=lane&31, row=(reg&3)+8*(reg>>2)+4*(lane>>5)
// MODE 0: fused QKV epilogue; Q scaled by 1/32 (folded logit scale).
// MODE 2: bf16 out, row-major ldc, z-strided   (logits, pre-scaled Q)
// MODE 3: fp32 out, row-major ldc, z-strided   (attn @ V^T)
// ============================================================================
template<int MODE>
__global__ __launch_bounds__(256)
void gemm_bt(const u16* __restrict__ Ain, const u16* __restrict__ Bin,
             void* __restrict__ Cv,
             const float* __restrict__ b0, const float* __restrict__ b1,
             const float* __restrict__ b2,
             int lda, int ldb, int ldc, int K,
             unsigned long long sA, unsigned long long sB, unsigned long long sC,
             int nbx, int nby)
{
  constexpr int BM = 128, BK = 32;
  __shared__ alignas(16) u16 As[2 * BM * BK];   // 16 KiB
  __shared__ alignas(16) u16 Bs[2 * BM * BK];   // 16 KiB

  // XCD-chunk + group-m swizzle
  const int nbxy = nbx * nby;
  const int bid  = blockIdx.x;
  const int flat = (bid & 7) * ((int)gridDim.x >> 3) + (bid >> 3);
  const int z    = flat / nbxy;
  const int rr   = flat - z * nbxy;
  const int width = nbx << 3;
  const int gid  = rr / width;
  const int rw   = rr - gid * width;
  const int by   = (gid << 3) + (rw & 7);
  const int bx   = rw >> 3;

  const u16* A = Ain + z * sA;
  const u16* B = Bin + z * sB;

  const int tid  = threadIdx.x;
  const int wave = tid >> 6;
  const int lane = tid & 63;
  const int l32  = lane & 31;
  const int half = lane >> 5;
  const int wr   = wave >> 1;     // 2x2 wave grid, 64x64 per wave
  const int wc   = wave & 1;

  const int m0 = by * BM;
  const int n0 = bx * BM;

  // --- staging: per wave, one gload = 16 rows x 4 chunks (1 KiB).
  // lane -> row = wave*16 + (lane>>2), pos = lane&3;
  // source chunk g = pos ^ ((row>>1)&3); wave*16 and j*64 are 0 mod 4
  // after >>1, so g = pos ^ (((lane>>2)>>1)&3) is lane-constant.
  const int lr2 = lane >> 2;                    // 0..15
  const int pos = lane & 3;
  const int gch = pos ^ ((lr2 >> 1) & 3);       // swizzled source chunk
  const u16* Ag = A + (size_t)(m0 + wave * 16 + lr2) * lda + gch * 8;
  const u16* Bg = B + (size_t)(n0 + wave * 16 + lr2) * ldb + gch * 8;
  u16* Asb = &As[(wave * 16) * BK];             // wave-uniform LDS base
  u16* Bsb = &Bs[(wave * 16) * BK];             // (+ buf*4096, + j*2048)

  f32x16 acc[2][2];
  #pragma unroll
  for (int i = 0; i < 2; ++i)
    #pragma unroll
    for (int j = 0; j < 2; ++j)
      #pragma unroll
      for (int r = 0; r < 16; ++r)
        acc[i][j][r] = 0.f;

  // prologue: stage tile 0 -> buf 0
  gload_lds16(Ag,                    Asb);
  gload_lds16(Ag + (size_t)64 * lda, Asb + 2048);
  gload_lds16(Bg,                    Bsb);
  gload_lds16(Bg + (size_t)64 * ldb, Bsb + 2048);
  __syncthreads();

  const int NT = K >> 5;   // BK=32 tiles
  for (int t = 0; t < NT; ++t) {
    const int cur = (t & 1) * 4096;             // u16 offset of current buf
    const int nxt = cur ^ 4096;
    const int kn  = (t + 1 < NT) ? (t + 1) * 32 : 0;   // wrap: harmless re-stage

    // issue NEXT tile's staging first — latency hides under this tile's compute
    gload_lds16(Ag + kn,                    Asb + nxt);
    gload_lds16(Ag + (size_t)64 * lda + kn, Asb + nxt + 2048);
    gload_lds16(Bg + kn,                    Bsb + nxt);
    gload_lds16(Bg + (size_t)64 * ldb + kn, Bsb + nxt + 2048);

    #pragma unroll
    for (int ks = 0; ks < 2; ++ks) {
      bf16x8 af[2], bfr[2];
      #pragma unroll
      for (int ti = 0; ti < 2; ++ti) {
        const int row = wr * 64 + ti * 32 + l32;
        const int ch  = ((ks * 2 + half) ^ ((l32 >> 1) & 3)) * 8;
        af[ti] = *(const bf16x8*)&As[cur + row * BK + ch];
      }
      #pragma unroll
      for (int tj = 0; tj < 2; ++tj) {
        const int row = wc * 64 + tj * 32 + l32;
        const int ch  = ((ks * 2 + half) ^ ((l32 >> 1) & 3)) * 8;
        bfr[tj] = *(const bf16x8*)&Bs[cur + row * BK + ch];
      }
      #pragma unroll
      for (int ti = 0; ti < 2; ++ti)
        #pragma unroll
        for (int tj = 0; tj < 2; ++tj)
          acc[ti][tj] = __builtin_amdgcn_mfma_f32_32x32x16_bf16(af[ti], bfr[tj], acc[ti][tj], 0, 0, 0);
    }
    // one barrier per tile; its vmcnt(0) drains the stage issued above
    // (leash = this tile's compute) and publishes it to all waves.
    __syncthreads();
  }

  // epilogue lane mapping (32x32 C/D map)
  const int colb = n0 + wc * 64 + l32;          // + tj*32
  const int rowb = m0 + wr * 64 + 4 * half;     // + ti*32 + (reg&3) + 8*(reg>>2)

  if constexpr (MODE == 0) {
    const int g = n0 >> 10;                     // 0=Q, 1=K, 2=V (block-uniform)
    u16* Qb = (u16*)Cv;
    if (g < 2) {
      u16* Cb = Qb + (size_t)g * 8388608ULL;
      const float* bp = (g == 0) ? b0 : b1;
      const float qs = (g == 0) ? 0.03125f : 1.0f;   // fold 1/sqrt(1024) into Q
      #pragma unroll
      for (int tj = 0; tj < 2; ++tj) {
        const int col = (colb + tj * 32) & 1023;
        const float bv = bp[col];
        #pragma unroll
        for (int ti = 0; ti < 2; ++ti)
          #pragma unroll
          for (int g4 = 0; g4 < 4; ++g4)
            #pragma unroll
            for (int r = 0; r < 4; ++r) {
              const int row = rowb + ti * 32 + g4 * 8 + r;
              Cb[(size_t)row * 1024 + col] = f2bf((acc[ti][tj][g4 * 4 + r] + bv) * qs);
            }
      }
    } else {
      u16* Vt = Qb + 16777216ULL;               // [4][1024][2048]
      #pragma unroll
      for (int tj = 0; tj < 2; ++tj) {
        const int col = (colb + tj * 32) & 1023;
        const float bv = b2[col];
        #pragma unroll
        for (int ti = 0; ti < 2; ++ti)
          #pragma unroll
          for (int g4 = 0; g4 < 4; ++g4) {
            const int row = rowb + ti * 32 + g4 * 8;   // 4 consecutive s
            u16x4 o;
            #pragma unroll
            for (int r = 0; r < 4; ++r) o[r] = f2bf(acc[ti][tj][g4 * 4 + r] + bv);
            const size_t idx = ((size_t)((row >> 11) * 1024 + col)) * 2048 + (row & 2047);
            *(u16x4*)&Vt[idx] = o;
          }
      }
    }
  } else if constexpr (MODE == 2) {
    u16* Cb = (u16*)Cv + z * sC;
    #pragma unroll
    for (int tj = 0; tj < 2; ++tj) {
      const int col = colb + tj * 32;
      #pragma unroll
      for (int ti = 0; ti < 2; ++ti)
        #pragma unroll
        for (int g4 = 0; g4 < 4; ++g4)
          #pragma unroll
          for (int r = 0; r < 4; ++r) {
            const int row = rowb + ti * 32 + g4 * 8 + r;
            Cb[(size_t)row * ldc + col] = f2bf(acc[ti][tj][g4 * 4 + r]);
          }
    }
  } else {
    float* Cf = (float*)Cv + z * sC;
    #pragma unroll
    for (int tj = 0; tj < 2; ++tj) {
      const int col = colb + tj * 32;
      #pragma unroll
      for (int ti = 0; ti < 2; ++ti)
        #pragma unroll
        for (int g4 = 0; g4 < 4; ++g4)
          #pragma unroll
          for (int r = 0; r < 4; ++r) {
            const int row = rowb + ti * 32 + g4 * 8 + r;
            Cf[(size_t)row * ldc + col] = acc[ti][tj][g4 * 4 + r];
          }
    }
  }
}

// one block per row; reads bf16 logits, writes fp32 attn to d_out and
// bf16 attn in-place (input to the PV gemm).
__global__ __launch_bounds__(256)
void softmax_rows(u16* __restrict__ logits, float* __restrict__ attn) {
  const int row = blockIdx.x;
  const int tid = threadIdx.x;
  u16*   lp = logits + (size_t)row * 2048 + tid * 8;
  float* ap = attn   + (size_t)row * 2048 + tid * 8;

  u16x8 raw = *(const u16x8*)lp;
  float v[8];
  #pragma unroll
  for (int j = 0; j < 8; ++j) v[j] = bf2f(raw[j]);

  float mx = v[0];
  #pragma unroll
  for (int j = 1; j < 8; ++j) mx = fmaxf(mx, v[j]);
  #pragma unroll
  for (int o = 32; o > 0; o >>= 1) mx = fmaxf(mx, __shfl_xor(mx, o, 64));

  __shared__ float smax[4], ssum[4];
  const int wv = tid >> 6, ln = tid & 63;
  if (ln == 0) smax[wv] = mx;
  __syncthreads();
  mx = fmaxf(fmaxf(smax[0], smax[1]), fmaxf(smax[2], smax[3]));

  float s = 0.f;
  #pragma unroll
  for (int j = 0; j < 8; ++j) { v[j] = __expf(v[j] - mx); s += v[j]; }
  #pragma unroll
  for (int o = 32; o > 0; o >>= 1) s += __shfl_xor(s, o, 64);
  if (ln == 0) ssum[wv] = s;
  __syncthreads();
  s = (ssum[0] + ssum[1]) + (ssum[2] + ssum[3]);
  const float inv = 1.f / s;

  u16x8 ob;
  #pragma unroll
  for (int j = 0; j < 8; ++j) { v[j] *= inv; ob[j] = f2bf(v[j]); }
  float4* apv = (float4*)ap;
  apv[0] = make_float4(v[0], v[1], v[2], v[3]);
  apv[1] = make_float4(v[4], v[5], v[6], v[7]);
  *(u16x8*)lp = ob;
}

extern "C" void kernel_launch(void* const* d_in, const int* in_sizes, int n_in,
                              void* d_out, int out_size, void* d_ws, size_t ws_size,
                              hipStream_t stream) {
  (void)in_sizes; (void)n_in; (void)out_size; (void)ws_size;
  const float* x    = (const float*)d_in[0];
  const float* wq_w = (const float*)d_in[1];
  const float* wq_b = (const float*)d_in[2];
  const float* wk_w = (const float*)d_in[3];
  const float* wk_b = (const float*)d_in[4];
  const float* wv_w = (const float*)d_in[5];
  const float* wv_b = (const float*)d_in[6];

  float* attn = (float*)d_out;                 // [4,2048,2048] fp32
  float* outp = attn + 16777216ULL;            // [4,2048,1024] fp32

  // ws layout (u16 elems): x_bf(8M) | wcat(3M) | Q(8M) | K(8M) | V^T(8M) | logits(16M)
  u16* xb   = (u16*)d_ws;
  u16* wcat = xb   + 8388608ULL;
  u16* Qb   = wcat + 3145728ULL;   // [8192][1024], pre-scaled by 1/32
  u16* Kb   = Qb   + 8388608ULL;   // [8192][1024]
  u16* Vt   = Kb   + 8388608ULL;   // [4][1024][2048]
  u16* Lg   = Vt   + 8388608ULL;   // [4][2048][2048]

  cvt_f32_bf16<<<8192, 256, 0, stream>>>(x, xb);
  cvt_w3<<<3072, 256, 0, stream>>>(wq_w, wk_w, wv_w, wcat);

  // fused QKV: M=8192, N=3072, K=1024
  gemm_bt<0><<<1536, 256, 0, stream>>>(xb, wcat, Qb, wq_b, wk_b, wv_b,
                                       1024, 1024, 1024, 1024, 0, 0, 0, 24, 64);

  // logits = (Q/32) K^T per batch: M=N=2048, K=1024
  gemm_bt<2><<<1024, 256, 0, stream>>>(Qb, Kb, Lg, nullptr, nullptr, nullptr,
                                       1024, 1024, 2048, 1024,
                                       2097152ULL, 2097152ULL, 4194304ULL, 16, 16);

  softmax_rows<<<8192, 256, 0, stream>>>(Lg, attn);

  // out = attn V: M=2048, N=1024, K=2048 per batch
  gemm_bt<3><<<512, 256, 0, stream>>>(Lg, Vt, outp, nullptr, nullptr, nullptr,
                                      2048, 2048, 1024, 2048,
                                      4194304ULL, 2097152ULL, 2097152ULL, 8, 16);
}

// Round 4
// 331.887 us; speedup vs baseline: 1.0089x; 1.0089x over previous
//
#include <hip/hip_runtime.h>

typedef unsigned short u16;
typedef u16 u16x4 __attribute__((ext_vector_type(4)));
typedef u16 u16x8 __attribute__((ext_vector_type(8)));
typedef __bf16 bf16x8 __attribute__((ext_vector_type(8)));
typedef float f32x16 __attribute__((ext_vector_type(16)));

static __device__ __forceinline__ u16 f2bf(float f) {
  unsigned u = __builtin_bit_cast(unsigned, f);
  u += 0x7fffu + ((u >> 16) & 1u);   // RNE; finite inputs
  return (u16)(u >> 16);
}
static __device__ __forceinline__ float bf2f(u16 h) {
  return __builtin_bit_cast(float, ((unsigned)h) << 16);
}

// async global->LDS, 16B/lane. LDS dest = wave-uniform base + lane*16.
static __device__ __forceinline__ void gload_lds16(const u16* g, u16* l) {
  u16* gn = const_cast<u16*>(g);
  __builtin_amdgcn_global_load_lds(
      (__attribute__((address_space(1))) unsigned int*)gn,
      (__attribute__((address_space(3))) unsigned int*)l,
      16, 0, 0);
}

__global__ __launch_bounds__(256)
void cvt_f32_bf16(const float* __restrict__ in, u16* __restrict__ out) {
  const int i = blockIdx.x * 256 + threadIdx.x;
  float4 f = ((const float4*)in)[i];
  u16x4 o = { f2bf(f.x), f2bf(f.y), f2bf(f.z), f2bf(f.w) };
  ((u16x4*)out)[i] = o;
}

__global__ __launch_bounds__(256)
void cvt_w3(const float* __restrict__ a, const float* __restrict__ b,
            const float* __restrict__ c, u16* __restrict__ out) {
  const int blk = blockIdx.x;       // 0..3071
  const int w = blk >> 10;
  const float* src = (w == 0) ? a : (w == 1) ? b : c;
  const int i = (blk & 1023) * 256 + threadIdx.x;
  float4 f = ((const float4*)src)[i];
  u16x4 o = { f2bf(f.x), f2bf(f.y), f2bf(f.z), f2bf(f.w) };
  ((u16x4*)(out + (size_t)w * 1048576ULL))[i] = o;
}

// ============================================================================
// 128x128 GEMM, C[m][n] = sum_k A[m][k]*B[n][k], k-contiguous inputs.
// mfma_f32_32x32x16_bf16; 4 waves (2x2), wave tile 64x64 = 2x2 of 32x32.
//
// ROUND-4 CHANGE (T4 counted-vmcnt, depth-2 prefetch, occupancy-preserving):
// BK=32, LDS TRIPLE-buffered [3][128x32] A + B = 48 KiB -> 3 blocks/CU
// (same as round-0's VGPR-bound 3; avoids m132's 64KB 2-block trap).
// Tile t: stage tile t+2 into slot (t+2)%3 (4 gloads), compute tile t from
// slot t%3, then ONE fused asm { s_waitcnt vmcnt(4) lgkmcnt(0); s_barrier }.
// vmcnt(4) drains exactly tile t+1's 4 loads — whose leash was TWO full
// tiles of compute (~600-800 cyc >= load latency) — and leaves t+2's 4 in
// flight across the barrier (never vmcnt(0) in-loop).
// Safety: lgkmcnt(0) before barrier => my reads of slot t%3 are done before
// anyone's post-barrier stage overwrites it (overwrite comes at top of t+1,
// after the barrier); vmcnt(4) before barrier => every wave's t+1 stage
// complete when all pass => slot (t+1)%3 fully published. Final vmcnt(0)
// drains wrap stages before LDS is released.
//
// LDS swizzle (4 chunks of 16B per row): pos p holds global chunk
// p ^ ((row>>1)&3) — residual conflicts hidden at this structure (m252).
// A/B frag: [row=lane&31][k = ks*16 + (lane>>5)*8 + j]
// C/D frag (m74/m101): col=lane&31, row=(reg&3)+8*(reg>>2)+4*(lane>>5)
// MODE 0: fused QKV epilogue; Q scaled by 1/32 (folded logit scale).
// MODE 2: bf16 out, row-major ldc, z-strided   (logits, pre-scaled Q)
// MODE 3: fp32 out, row-major ldc, z-strided   (attn @ V^T)
// ============================================================================
template<int MODE>
__global__ __launch_bounds__(256)
void gemm_bt(const u16* __restrict__ Ain, const u16* __restrict__ Bin,
             void* __restrict__ Cv,
             const float* __restrict__ b0, const float* __restrict__ b1,
             const float* __restrict__ b2,
             int lda, int ldb, int ldc, int K,
             unsigned long long sA, unsigned long long sB, unsigned long long sC,
             int nbx, int nby)
{
  constexpr int BM = 128, BK = 32;
  constexpr int SLOT = BM * BK;                 // 4096 u16 = 8 KiB per slot
  __shared__ alignas(16) u16 As[3 * SLOT];      // 24 KiB
  __shared__ alignas(16) u16 Bs[3 * SLOT];      // 24 KiB

  // XCD-chunk + group-m swizzle
  const int nbxy = nbx * nby;
  const int bid  = blockIdx.x;
  const int flat = (bid & 7) * ((int)gridDim.x >> 3) + (bid >> 3);
  const int z    = flat / nbxy;
  const int rr   = flat - z * nbxy;
  const int width = nbx << 3;
  const int gid  = rr / width;
  const int rw   = rr - gid * width;
  const int by   = (gid << 3) + (rw & 7);
  const int bx   = rw >> 3;

  const u16* A = Ain + z * sA;
  const u16* B = Bin + z * sB;

  const int tid  = threadIdx.x;
  const int wave = tid >> 6;
  const int lane = tid & 63;
  const int l32  = lane & 31;
  const int half = lane >> 5;
  const int wr   = wave >> 1;     // 2x2 wave grid, 64x64 per wave
  const int wc   = wave & 1;

  const int m0 = by * BM;
  const int n0 = bx * BM;

  // staging: per wave, one gload = 16 rows x 4 chunks (1 KiB).
  // lane -> row = wave*16 + (lane>>2), pos = lane&3;
  // source chunk g = pos ^ ((row>>1)&3) (row offsets are 0 mod 4 per instr).
  const int lr2 = lane >> 2;                    // 0..15
  const int pos = lane & 3;
  const int gch = pos ^ ((lr2 >> 1) & 3);       // swizzled source chunk
  const u16* Ag = A + (size_t)(m0 + wave * 16 + lr2) * lda + gch * 8;
  const u16* Bg = B + (size_t)(n0 + wave * 16 + lr2) * ldb + gch * 8;
  u16* Asb = &As[(wave * 16) * BK];             // wave-uniform LDS base
  u16* Bsb = &Bs[(wave * 16) * BK];             // (+ slot, + j*2048)

  f32x16 acc[2][2];
  #pragma unroll
  for (int i = 0; i < 2; ++i)
    #pragma unroll
    for (int j = 0; j < 2; ++j)
      #pragma unroll
      for (int r = 0; r < 16; ++r)
        acc[i][j][r] = 0.f;

  // prologue: stage tile 0 -> slot 0, tile 1 -> slot 1; wait for tile 0 only.
  gload_lds16(Ag,                         Asb);
  gload_lds16(Ag + (size_t)64 * lda,      Asb + 2048);
  gload_lds16(Bg,                         Bsb);
  gload_lds16(Bg + (size_t)64 * ldb,      Bsb + 2048);
  gload_lds16(Ag + 32,                    Asb + SLOT);
  gload_lds16(Ag + (size_t)64 * lda + 32, Asb + SLOT + 2048);
  gload_lds16(Bg + 32,                    Bsb + SLOT);
  gload_lds16(Bg + (size_t)64 * ldb + 32, Bsb + SLOT + 2048);
  asm volatile("s_waitcnt vmcnt(4) lgkmcnt(0)\n\ts_barrier" ::: "memory");

  const int NT = K >> 5;   // BK=32 tiles (>= 2 at all call sites)
  int cur = 0;             // u16 offset of slot t%3
  for (int t = 0; t < NT; ++t) {
    int s2 = cur + 2 * SLOT; if (s2 >= 3 * SLOT) s2 -= 3 * SLOT;   // slot (t+2)%3
    const int k2 = (t + 2 < NT) ? (t + 2) * 32 : 0;   // wrap: harmless re-stage

    // stage tile t+2 — its forced wait is two tiles away (leash >= latency)
    gload_lds16(Ag + k2,                    Asb + s2);
    gload_lds16(Ag + (size_t)64 * lda + k2, Asb + s2 + 2048);
    gload_lds16(Bg + k2,                    Bsb + s2);
    gload_lds16(Bg + (size_t)64 * ldb + k2, Bsb + s2 + 2048);

    #pragma unroll
    for (int ks = 0; ks < 2; ++ks) {
      bf16x8 af[2], bfr[2];
      #pragma unroll
      for (int ti = 0; ti < 2; ++ti) {
        const int row = wr * 64 + ti * 32 + l32;
        const int ch  = ((ks * 2 + half) ^ ((l32 >> 1) & 3)) * 8;
        af[ti] = *(const bf16x8*)&As[cur + row * BK + ch];
      }
      #pragma unroll
      for (int tj = 0; tj < 2; ++tj) {
        const int row = wc * 64 + tj * 32 + l32;
        const int ch  = ((ks * 2 + half) ^ ((l32 >> 1) & 3)) * 8;
        bfr[tj] = *(const bf16x8*)&Bs[cur + row * BK + ch];
      }
      #pragma unroll
      for (int ti = 0; ti < 2; ++ti)
        #pragma unroll
        for (int tj = 0; tj < 2; ++tj)
          acc[ti][tj] = __builtin_amdgcn_mfma_f32_32x32x16_bf16(af[ti], bfr[tj], acc[ti][tj], 0, 0, 0);
    }

    // counted drain: clears tile t+1's 4 loads (2-tile leash), keeps t+2's
    // 4 in flight; lgkmcnt(0) protects slot t%3 from the post-barrier
    // overwrite; barrier publishes slot t+1 to all waves.
    asm volatile("s_waitcnt vmcnt(4) lgkmcnt(0)\n\ts_barrier" ::: "memory");

    cur += SLOT; if (cur == 3 * SLOT) cur = 0;
  }
  asm volatile("s_waitcnt vmcnt(0)" ::: "memory");   // drain wrap stages before LDS dies

  // epilogue lane mapping (32x32 C/D map)
  const int colb = n0 + wc * 64 + l32;          // + tj*32
  const int rowb = m0 + wr * 64 + 4 * half;     // + ti*32 + (reg&3) + 8*(reg>>2)

  if constexpr (MODE == 0) {
    const int g = n0 >> 10;                     // 0=Q, 1=K, 2=V (block-uniform)
    u16* Qb = (u16*)Cv;
    if (g < 2) {
      u16* Cb = Qb + (size_t)g * 8388608ULL;
      const float* bp = (g == 0) ? b0 : b1;
      const float qs = (g == 0) ? 0.03125f : 1.0f;   // fold 1/sqrt(1024) into Q
      #pragma unroll
      for (int tj = 0; tj < 2; ++tj) {
        const int col = (colb + tj * 32) & 1023;
        const float bv = bp[col];
        #pragma unroll
        for (int ti = 0; ti < 2; ++ti)
          #pragma unroll
          for (int g4 = 0; g4 < 4; ++g4)
            #pragma unroll
            for (int r = 0; r < 4; ++r) {
              const int row = rowb + ti * 32 + g4 * 8 + r;
              Cb[(size_t)row * 1024 + col] = f2bf((acc[ti][tj][g4 * 4 + r] + bv) * qs);
            }
      }
    } else {
      u16* Vt = Qb + 16777216ULL;               // [4][1024][2048]
      #pragma unroll
      for (int tj = 0; tj < 2; ++tj) {
        const int col = (colb + tj * 32) & 1023;
        const float bv = b2[col];
        #pragma unroll
        for (int ti = 0; ti < 2; ++ti)
          #pragma unroll
          for (int g4 = 0; g4 < 4; ++g4) {
            const int row = rowb + ti * 32 + g4 * 8;   // 4 consecutive s
            u16x4 o;
            #pragma unroll
            for (int r = 0; r < 4; ++r) o[r] = f2bf(acc[ti][tj][g4 * 4 + r] + bv);
            const size_t idx = ((size_t)((row >> 11) * 1024 + col)) * 2048 + (row & 2047);
            *(u16x4*)&Vt[idx] = o;
          }
      }
    }
  } else if constexpr (MODE == 2) {
    u16* Cb = (u16*)Cv + z * sC;
    #pragma unroll
    for (int tj = 0; tj < 2; ++tj) {
      const int col = colb + tj * 32;
      #pragma unroll
      for (int ti = 0; ti < 2; ++ti)
        #pragma unroll
        for (int g4 = 0; g4 < 4; ++g4)
          #pragma unroll
          for (int r = 0; r < 4; ++r) {
            const int row = rowb + ti * 32 + g4 * 8 + r;
            Cb[(size_t)row * ldc + col] = f2bf(acc[ti][tj][g4 * 4 + r]);
          }
    }
  } else {
    float* Cf = (float*)Cv + z * sC;
    #pragma unroll
    for (int tj = 0; tj < 2; ++tj) {
      const int col = colb + tj * 32;
      #pragma unroll
      for (int ti = 0; ti < 2; ++ti)
        #pragma unroll
        for (int g4 = 0; g4 < 4; ++g4)
          #pragma unroll
          for (int r = 0; r < 4; ++r) {
            const int row = rowb + ti * 32 + g4 * 8 + r;
            Cf[(size_t)row * ldc + col] = acc[ti][tj][g4 * 4 + r];
          }
    }
  }
}

// one block per row; reads bf16 logits, writes fp32 attn to d_out and
// bf16 attn in-place (input to the PV gemm).
__global__ __launch_bounds__(256)
void softmax_rows(u16* __restrict__ logits, float* __restrict__ attn) {
  const int row = blockIdx.x;
  const int tid = threadIdx.x;
  u16*   lp = logits + (size_t)row * 2048 + tid * 8;
  float* ap = attn   + (size_t)row * 2048 + tid * 8;

  u16x8 raw = *(const u16x8*)lp;
  float v[8];
  #pragma unroll
  for (int j = 0; j < 8; ++j) v[j] = bf2f(raw[j]);

  float mx = v[0];
  #pragma unroll
  for (int j = 1; j < 8; ++j) mx = fmaxf(mx, v[j]);
  #pragma unroll
  for (int o = 32; o > 0; o >>= 1) mx = fmaxf(mx, __shfl_xor(mx, o, 64));

  __shared__ float smax[4], ssum[4];
  const int wv = tid >> 6, ln = tid & 63;
  if (ln == 0) smax[wv] = mx;
  __syncthreads();
  mx = fmaxf(fmaxf(smax[0], smax[1]), fmaxf(smax[2], smax[3]));

  float s = 0.f;
  #pragma unroll
  for (int j = 0; j < 8; ++j) { v[j] = __expf(v[j] - mx); s += v[j]; }
  #pragma unroll
  for (int o = 32; o > 0; o >>= 1) s += __shfl_xor(s, o, 64);
  if (ln == 0) ssum[wv] = s;
  __syncthreads();
  s = (ssum[0] + ssum[1]) + (ssum[2] + ssum[3]);
  const float inv = 1.f / s;

  u16x8 ob;
  #pragma unroll
  for (int j = 0; j < 8; ++j) { v[j] *= inv; ob[j] = f2bf(v[j]); }
  float4* apv = (float4*)ap;
  apv[0] = make_float4(v[0], v[1], v[2], v[3]);
  apv[1] = make_float4(v[4], v[5], v[6], v[7]);
  *(u16x8*)lp = ob;
}

extern "C" void kernel_launch(void* const* d_in, const int* in_sizes, int n_in,
                              void* d_out, int out_size, void* d_ws, size_t ws_size,
                              hipStream_t stream) {
  (void)in_sizes; (void)n_in; (void)out_size; (void)ws_size;
  const float* x    = (const float*)d_in[0];
  const float* wq_w = (const float*)d_in[1];
  const float* wq_b = (const float*)d_in[2];
  const float* wk_w = (const float*)d_in[3];
  const float* wk_b = (const float*)d_in[4];
  const float* wv_w = (const float*)d_in[5];
  const float* wv_b = (const float*)d_in[6];

  float* attn = (float*)d_out;                 // [4,2048,2048] fp32
  float* outp = attn + 16777216ULL;            // [4,2048,1024] fp32

  // ws layout (u16 elems): x_bf(8M) | wcat(3M) | Q(8M) | K(8M) | V^T(8M) | logits(16M)
  u16* xb   = (u16*)d_ws;
  u16* wcat = xb   + 8388608ULL;
  u16* Qb   = wcat + 3145728ULL;   // [8192][1024], pre-scaled by 1/32
  u16* Kb   = Qb   + 8388608ULL;   // [8192][1024]
  u16* Vt   = Kb   + 8388608ULL;   // [4][1024][2048]
  u16* Lg   = Vt   + 8388608ULL;   // [4][2048][2048]

  cvt_f32_bf16<<<8192, 256, 0, stream>>>(x, xb);
  cvt_w3<<<3072, 256, 0, stream>>>(wq_w, wk_w, wv_w, wcat);

  // fused QKV: M=8192, N=3072, K=1024
  gemm_bt<0><<<1536, 256, 0, stream>>>(xb, wcat, Qb, wq_b, wk_b, wv_b,
                                       1024, 1024, 1024, 1024, 0, 0, 0, 24, 64);

  // logits = (Q/32) K^T per batch: M=N=2048, K=1024
  gemm_bt<2><<<1024, 256, 0, stream>>>(Qb, Kb, Lg, nullptr, nullptr, nullptr,
                                       1024, 1024, 2048, 1024,
                                       2097152ULL, 2097152ULL, 4194304ULL, 16, 16);

  softmax_rows<<<8192, 256, 0, stream>>>(Lg, attn);

  // out = attn V: M=2048, N=1024, K=2048 per batch
  gemm_bt<3><<<512, 256, 0, stream>>>(Lg, Vt, outp, nullptr, nullptr, nullptr,
                                      2048, 2048, 1024, 2048,
                                      4194304ULL, 2097152ULL, 2097152ULL, 8, 16);
}

// Round 5
// 320.517 us; speedup vs baseline: 1.0447x; 1.0355x over previous
//
#include <hip/hip_runtime.h>

typedef unsigned short u16;
typedef u16 u16x4 __attribute__((ext_vector_type(4)));
typedef u16 u16x8 __attribute__((ext_vector_type(8)));
typedef __bf16 bf16x8 __attribute__((ext_vector_type(8)));
typedef float f32x4 __attribute__((ext_vector_type(4)));

static __device__ __forceinline__ u16 f2bf(float f) {
  unsigned u = __builtin_bit_cast(unsigned, f);
  u += 0x7fffu + ((u >> 16) & 1u);   // RNE; finite inputs
  return (u16)(u >> 16);
}
static __device__ __forceinline__ float bf2f(u16 h) {
  return __builtin_bit_cast(float, ((unsigned)h) << 16);
}

// async global->LDS, 16B/lane. LDS dest = wave-uniform base + lane*16.
static __device__ __forceinline__ void gload_lds16(const u16* g, u16* l) {
  u16* gn = const_cast<u16*>(g);
  __builtin_amdgcn_global_load_lds(
      (__attribute__((address_space(1))) unsigned int*)gn,
      (__attribute__((address_space(3))) unsigned int*)l,
      16, 0, 0);
}

__global__ __launch_bounds__(256)
void cvt_f32_bf16(const float* __restrict__ in, u16* __restrict__ out) {
  const int i = blockIdx.x * 256 + threadIdx.x;
  float4 f = ((const float4*)in)[i];
  u16x4 o = { f2bf(f.x), f2bf(f.y), f2bf(f.z), f2bf(f.w) };
  ((u16x4*)out)[i] = o;
}

__global__ __launch_bounds__(256)
void cvt_w3(const float* __restrict__ a, const float* __restrict__ b,
            const float* __restrict__ c, u16* __restrict__ out) {
  const int blk = blockIdx.x;       // 0..3071
  const int w = blk >> 10;
  const float* src = (w == 0) ? a : (w == 1) ? b : c;
  const int i = (blk & 1023) * 256 + threadIdx.x;
  float4 f = ((const float4*)src)[i];
  u16x4 o = { f2bf(f.x), f2bf(f.y), f2bf(f.z), f2bf(f.w) };
  ((u16x4*)(out + (size_t)w * 1048576ULL))[i] = o;
}

// ============================================================================
// 256x128 GEMM, C[m][n] = sum_k A[m][k]*B[n][k], k-contiguous inputs.
//
// ROUND-5 REDESIGN (LDS-read-ratio fix). Diagnosis: the 64x64 wave tile's
// frag traffic (1 KB LDS per MFMA, bytes:FLOP 1:32) makes every prior
// variant LDS-read-bound (~768 cyc LDS vs ~310 cyc matrix per tile —
// MfmaUtil pinned at ~27% across R0/R3/R4 no matter the schedule), with a
// measured 4 cyc/read 4-way bank conflict in the 32-row read pattern.
//
// Fix: wave tile 128x64 via mfma_f32_16x16x32_bf16 (8 mi x 4 ni frags,
// ratio 1:42.7) using the R1-verified CONFLICT-FREE layout (16-row l16
// spans, l4-XOR slots; measured SQ_LDS_BANK_CONFLICT == 0), inside the
// R0-proven schedule (single-buffer, stage -> sync -> compute -> sync).
// Block 256x128, 4 waves (2 m-halves x 2 n-halves), BK=64, LDS 48 KiB
// single-buffered -> 2 blocks/CU (VGPR ~210, __launch_bounds__(256,2)).
// Per block-tile: 96 conflict-free ds_read_b128 (~1152 cyc) vs 256 MFMA
// (~1242 cyc) — matrix-balanced.
//
// LDS layouts (linear dest for global_load_lds; swizzle on SOURCE addr):
//   As[256 rows][64 k] u16; 16B chunk at pos p holds global chunk
//     p ^ (row&7).
//   Bs[2 ks][128 rows][32 k] u16; chunk pos p holds global chunk
//     p ^ ((row>>1)&3).
// Frag reads (R1-verified):
//   A(mi,ks): row = wr*128+mi*16+l16, pos = (l4 ^ (l16&7)) ^ (ks<<2)
//   B(ni,ks): row = wc*64+ni*16+l16,  pos = l4 ^ ((l16>>1)&3)
// C/D 16x16x32 map (m89): col = lane&15, row = (lane>>4)*4 + reg.
//
// MODE 0: fused QKV epilogue; Q scaled by 1/32 (folded logit scale).
// MODE 2: bf16 out, row-major ldc, z-strided   (logits, pre-scaled Q)
// MODE 3: fp32 out, row-major ldc, z-strided   (attn @ V^T)
// ============================================================================
template<int MODE>
__global__ __launch_bounds__(256, 2)
void gemm_bt(const u16* __restrict__ Ain, const u16* __restrict__ Bin,
             void* __restrict__ Cv,
             const float* __restrict__ b0, const float* __restrict__ b1,
             const float* __restrict__ b2,
             int lda, int ldb, int ldc, int K,
             unsigned long long sA, unsigned long long sB, unsigned long long sC,
             int nbx, int nby)
{
  __shared__ alignas(16) u16 As[256 * 64];      // 32 KiB
  __shared__ alignas(16) u16 Bs[2 * 128 * 32];  // 16 KiB

  // XCD-chunk + group-m swizzle (grid % 8 == 0 at all call sites)
  const int nbxy = nbx * nby;
  const int bid  = blockIdx.x;
  const int flat = (bid & 7) * ((int)gridDim.x >> 3) + (bid >> 3);
  const int z    = flat / nbxy;
  const int rr   = flat - z * nbxy;
  const int width = nbx << 3;
  const int gid  = rr / width;
  const int rw   = rr - gid * width;
  const int by   = (gid << 3) + (rw & 7);
  const int bx   = rw >> 3;

  const u16* A = Ain + z * sA;
  const u16* B = Bin + z * sB;

  const int tid  = threadIdx.x;
  const int wave = tid >> 6;      // 0..3
  const int lane = tid & 63;
  const int l16  = lane & 15;
  const int l4   = (lane >> 4) & 3;
  const int wr   = wave >> 1;     // m-half (128 rows)
  const int wc   = wave & 1;      // n-half (64 rows)

  const int m0 = by << 8;         // 256-row M tile
  const int n0 = bx << 7;         // 128-row N tile

  // --- staging addresses (source carries the inverse swizzle) ---
  // A: wave stages 64 rows (8 instrs x 8 rows x 128B). lane -> row lane>>3,
  //    pos lane&7, src chunk = pos ^ (row&7) = (lane&7)^(lane>>3).
  const u16* Ag = A + (size_t)(m0 + wave * 64 + (lane >> 3)) * lda
                    + (((lane & 7) ^ (lane >> 3)) << 3);
  u16* Asb = &As[wave * 64 * 64];               // + j*512 per instr
  // B: wave stages 32 rows x both ks-halves (4 instrs x 16 rows x 64B).
  //    lane -> row lane>>2, pos lane&3, src chunk = pos ^ ((row>>1)&3)
  //    = (lane&3)^((lane>>3)&3).
  const u16* Bg = B + (size_t)(n0 + wave * 32 + (lane >> 2)) * ldb
                    + (((lane & 3) ^ ((lane >> 3) & 3)) << 3);
  u16* Bsb = &Bs[wave * 32 * 32];               // + ks*4096 + rh*512

  // --- fragment read bases (R1-verified, conflict-free) ---
  const int pA = l4 ^ (l16 & 7);
  const u16* ArdBase = As + (size_t)(wr * 128 + l16) * 64;   // + mi*1024 + ((pA^(ks<<2))<<3)
  const u16* BrdBase = Bs + (size_t)(wc * 64 + l16) * 32
                          + ((l4 ^ ((l16 >> 1) & 3)) << 3);  // + ks*4096 + ni*512

  f32x4 acc[8][4];
  #pragma unroll
  for (int i = 0; i < 8; ++i)
    #pragma unroll
    for (int j = 0; j < 4; ++j)
      #pragma unroll
      for (int r = 0; r < 4; ++r)
        acc[i][j][r] = 0.f;

  for (int k0 = 0; k0 < K; k0 += 64) {
    // stage tile: A 8 instrs, B 4 instrs per wave (48 KiB/block)
    #pragma unroll
    for (int j = 0; j < 8; ++j)
      gload_lds16(Ag + (size_t)(j * 8) * lda + k0, Asb + j * 512);
    gload_lds16(Bg + k0,                          Bsb);
    gload_lds16(Bg + (size_t)16 * ldb + k0,       Bsb + 512);
    gload_lds16(Bg + k0 + 32,                     Bsb + 4096);
    gload_lds16(Bg + (size_t)16 * ldb + k0 + 32,  Bsb + 4096 + 512);
    __syncthreads();

    #pragma unroll
    for (int ks = 0; ks < 2; ++ks) {
      bf16x8 af[8], bf[4];
      #pragma unroll
      for (int mi = 0; mi < 8; ++mi)
        af[mi] = *(const bf16x8*)(ArdBase + mi * 1024 + ((pA ^ (ks << 2)) << 3));
      #pragma unroll
      for (int ni = 0; ni < 4; ++ni)
        bf[ni] = *(const bf16x8*)(BrdBase + ks * 4096 + ni * 512);
      #pragma unroll
      for (int mi = 0; mi < 8; ++mi)
        #pragma unroll
        for (int ni = 0; ni < 4; ++ni)
          acc[mi][ni] = __builtin_amdgcn_mfma_f32_16x16x32_bf16(af[mi], bf[ni], acc[mi][ni], 0, 0, 0);
    }
    __syncthreads();
  }

  // epilogue: C/D 16x16x32 map: col = l16, row = l4*4 + reg (m89)
  const int colq = wc * 64;                      // + ni*16 + l16
  const int rowb = m0 + wr * 128 + l4 * 4;       // + mi*16 + r

  if constexpr (MODE == 0) {
    const int g = n0 >> 10;                      // 0=Q, 1=K, 2=V (block-uniform)
    if (g < 2) {
      u16* Cb = (u16*)Cv + (size_t)g * 8388608ULL;
      const float* bp = (g == 0) ? b0 : b1;
      const float qs = (g == 0) ? 0.03125f : 1.0f;   // fold 1/sqrt(1024) into Q
      #pragma unroll
      for (int ni = 0; ni < 4; ++ni) {
        const int col = (n0 + colq + ni * 16 + l16) & 1023;
        const float bv = bp[col];
        #pragma unroll
        for (int mi = 0; mi < 8; ++mi) {
          const int row = rowb + mi * 16;
          #pragma unroll
          for (int r = 0; r < 4; ++r)
            Cb[(size_t)(row + r) * 1024 + col] = f2bf((acc[mi][ni][r] + bv) * qs);
        }
      }
    } else {
      u16* Vt = (u16*)Cv + 16777216ULL;          // [4][1024][2048]
      #pragma unroll
      for (int ni = 0; ni < 4; ++ni) {
        const int col = (n0 + colq + ni * 16 + l16) & 1023;
        const float bv = b2[col];
        #pragma unroll
        for (int mi = 0; mi < 8; ++mi) {
          const int row = rowb + mi * 16;        // 4 consecutive s via reg idx
          u16x4 o;
          #pragma unroll
          for (int r = 0; r < 4; ++r) o[r] = f2bf(acc[mi][ni][r] + bv);
          const size_t idx = ((size_t)((row >> 11) * 1024 + col)) * 2048 + (row & 2047);
          *(u16x4*)&Vt[idx] = o;
        }
      }
    }
  } else if constexpr (MODE == 2) {
    u16* Cb = (u16*)Cv + (size_t)z * sC;
    #pragma unroll
    for (int ni = 0; ni < 4; ++ni) {
      const int col = n0 + colq + ni * 16 + l16;
      #pragma unroll
      for (int mi = 0; mi < 8; ++mi) {
        const int row = rowb + mi * 16;
        #pragma unroll
        for (int r = 0; r < 4; ++r)
          Cb[(size_t)(row + r) * ldc + col] = f2bf(acc[mi][ni][r]);
      }
    }
  } else {
    float* Cf = (float*)Cv + (size_t)z * sC;
    #pragma unroll
    for (int ni = 0; ni < 4; ++ni) {
      const int col = n0 + colq + ni * 16 + l16;
      #pragma unroll
      for (int mi = 0; mi < 8; ++mi) {
        const int row = rowb + mi * 16;
        #pragma unroll
        for (int r = 0; r < 4; ++r)
          Cf[(size_t)(row + r) * ldc + col] = acc[mi][ni][r];
      }
    }
  }
}

// one block per row; reads bf16 logits, writes fp32 attn to d_out and
// bf16 attn in-place (input to the PV gemm).
__global__ __launch_bounds__(256)
void softmax_rows(u16* __restrict__ logits, float* __restrict__ attn) {
  const int row = blockIdx.x;
  const int tid = threadIdx.x;
  u16*   lp = logits + (size_t)row * 2048 + tid * 8;
  float* ap = attn   + (size_t)row * 2048 + tid * 8;

  u16x8 raw = *(const u16x8*)lp;
  float v[8];
  #pragma unroll
  for (int j = 0; j < 8; ++j) v[j] = bf2f(raw[j]);

  float mx = v[0];
  #pragma unroll
  for (int j = 1; j < 8; ++j) mx = fmaxf(mx, v[j]);
  #pragma unroll
  for (int o = 32; o > 0; o >>= 1) mx = fmaxf(mx, __shfl_xor(mx, o, 64));

  __shared__ float smax[4], ssum[4];
  const int wv = tid >> 6, ln = tid & 63;
  if (ln == 0) smax[wv] = mx;
  __syncthreads();
  mx = fmaxf(fmaxf(smax[0], smax[1]), fmaxf(smax[2], smax[3]));

  float s = 0.f;
  #pragma unroll
  for (int j = 0; j < 8; ++j) { v[j] = __expf(v[j] - mx); s += v[j]; }
  #pragma unroll
  for (int o = 32; o > 0; o >>= 1) s += __shfl_xor(s, o, 64);
  if (ln == 0) ssum[wv] = s;
  __syncthreads();
  s = (ssum[0] + ssum[1]) + (ssum[2] + ssum[3]);
  const float inv = 1.f / s;

  u16x8 ob;
  #pragma unroll
  for (int j = 0; j < 8; ++j) { v[j] *= inv; ob[j] = f2bf(v[j]); }
  float4* apv = (float4*)ap;
  apv[0] = make_float4(v[0], v[1], v[2], v[3]);
  apv[1] = make_float4(v[4], v[5], v[6], v[7]);
  *(u16x8*)lp = ob;
}

extern "C" void kernel_launch(void* const* d_in, const int* in_sizes, int n_in,
                              void* d_out, int out_size, void* d_ws, size_t ws_size,
                              hipStream_t stream) {
  (void)in_sizes; (void)n_in; (void)out_size; (void)ws_size;
  const float* x    = (const float*)d_in[0];
  const float* wq_w = (const float*)d_in[1];
  const float* wq_b = (const float*)d_in[2];
  const float* wk_w = (const float*)d_in[3];
  const float* wk_b = (const float*)d_in[4];
  const float* wv_w = (const float*)d_in[5];
  const float* wv_b = (const float*)d_in[6];

  float* attn = (float*)d_out;                 // [4,2048,2048] fp32
  float* outp = attn + 16777216ULL;            // [4,2048,1024] fp32

  // ws layout (u16 elems): x_bf(8M) | wcat(3M) | Q(8M) | K(8M) | V^T(8M) | logits(16M)
  u16* xb   = (u16*)d_ws;
  u16* wcat = xb   + 8388608ULL;
  u16* Qb   = wcat + 3145728ULL;   // [8192][1024], pre-scaled by 1/32
  u16* Kb   = Qb   + 8388608ULL;   // [8192][1024]
  u16* Vt   = Kb   + 8388608ULL;   // [4][1024][2048]
  u16* Lg   = Vt   + 8388608ULL;   // [4][2048][2048]

  cvt_f32_bf16<<<8192, 256, 0, stream>>>(x, xb);
  cvt_w3<<<3072, 256, 0, stream>>>(wq_w, wk_w, wv_w, wcat);

  // fused QKV: M=8192, N=3072, K=1024  (256x128 tiles -> 32x24 = 768 blocks)
  gemm_bt<0><<<768, 256, 0, stream>>>(xb, wcat, Qb, wq_b, wk_b, wv_b,
                                      1024, 1024, 1024, 1024, 0, 0, 0, 24, 32);

  // logits = (Q/32) K^T per batch: M=N=2048, K=1024  (8x16x4 = 512 blocks)
  gemm_bt<2><<<512, 256, 0, stream>>>(Qb, Kb, Lg, nullptr, nullptr, nullptr,
                                      1024, 1024, 2048, 1024,
                                      2097152ULL, 2097152ULL, 4194304ULL, 16, 8);

  softmax_rows<<<8192, 256, 0, stream>>>(Lg, attn);

  // out = attn V: M=2048, N=1024, K=2048 per batch (8x8x4 = 256 blocks)
  gemm_bt<3><<<256, 256, 0, stream>>>(Lg, Vt, outp, nullptr, nullptr, nullptr,
                                      2048, 2048, 1024, 2048,
                                      4194304ULL, 2097152ULL, 2097152ULL, 8, 8);
}

// Round 6
// 314.158 us; speedup vs baseline: 1.0659x; 1.0202x over previous
//
#include <hip/hip_runtime.h>

typedef unsigned short u16;
typedef u16 u16x4 __attribute__((ext_vector_type(4)));
typedef u16 u16x8 __attribute__((ext_vector_type(8)));
typedef __bf16 bf16x8 __attribute__((ext_vector_type(8)));
typedef float f32x4 __attribute__((ext_vector_type(4)));
typedef float f32x16 __attribute__((ext_vector_type(16)));

static __device__ __forceinline__ u16 f2bf(float f) {
  unsigned u = __builtin_bit_cast(unsigned, f);
  u += 0x7fffu + ((u >> 16) & 1u);   // RNE; finite inputs
  return (u16)(u >> 16);
}
static __device__ __forceinline__ float bf2f(u16 h) {
  return __builtin_bit_cast(float, ((unsigned)h) << 16);
}

// async global->LDS, 16B/lane. LDS dest = wave-uniform base + lane*16.
static __device__ __forceinline__ void gload_lds16(const u16* g, u16* l) {
  u16* gn = const_cast<u16*>(g);
  __builtin_amdgcn_global_load_lds(
      (__attribute__((address_space(1))) unsigned int*)gn,
      (__attribute__((address_space(3))) unsigned int*)l,
      16, 0, 0);
}

__global__ __launch_bounds__(256)
void cvt_f32_bf16(const float* __restrict__ in, u16* __restrict__ out) {
  const int i = blockIdx.x * 256 + threadIdx.x;
  float4 f = ((const float4*)in)[i];
  u16x4 o = { f2bf(f.x), f2bf(f.y), f2bf(f.z), f2bf(f.w) };
  ((u16x4*)out)[i] = o;
}

__global__ __launch_bounds__(256)
void cvt_w3(const float* __restrict__ a, const float* __restrict__ b,
            const float* __restrict__ c, u16* __restrict__ out) {
  const int blk = blockIdx.x;       // 0..3071
  const int w = blk >> 10;
  const float* src = (w == 0) ? a : (w == 1) ? b : c;
  const int i = (blk & 1023) * 256 + threadIdx.x;
  float4 f = ((const float4*)src)[i];
  u16x4 o = { f2bf(f.x), f2bf(f.y), f2bf(f.z), f2bf(f.w) };
  ((u16x4*)(out + (size_t)w * 1048576ULL))[i] = o;
}

// ============================================================================
// 256x256 8-phase GEMM — template-faithful port (round 6).
// C[m][n] = sum_k A[m][k]*B[n][k]. 512 thr = 8 waves (wr=wave>>2: 2 m,
// wc=wave&3: 4 n); per-wave out 128x64 = 8mi x 4ni frags of
// mfma_f32_16x16x32_bf16. BK=64 split as two k-halves (kh) of 32.
//
// LDS: As[2 buf][2 kh][256 rows][32 k] u16 (64 KiB) + Bs same = 128 KiB.
// Stage unit = one (operand, kh) half-tile = 256x32 = 16 KiB = 2 gload
// calls (512 thr x 16B). Dest linear (tid*16B within plane); the 2-bit
// XOR swizzle rides the SOURCE: thread writes dest chunk p=tid&3 at
// row=c*128+(tid>>2) from global chunk p ^ ((row>>1)&3) (lane-const).
// Frag read (verified R5-class, 0 conflicts): row = (wr*128|wc*64)+X*16+l16,
// chunk = l4 ^ ((l16>>1)&3), plane (buf, ks).
//
// Phase p of the 8-phase iteration (tiles t->buf0, t+1->buf1):
//   compute quadrant: P1(t,mh0,k0) P2(t,mh1,k0) P3(t,mh0,k1) P4(t,mh1,k1)
//                     P5-P8 same on t+1. mh0 phases read 4A+4B frags,
//                     mh1 phases read 4A (B regs reused) — "4 or 8".
//   stage order:      P1:A(t+1)k1  P2:B(t+1)k1  P3:A(t+2)k0  P4:B(t+2)k0
//                     P5:A(t+2)k1  P6:B(t+2)k1  P7:A(t+3)k0  P8:B(t+3)k0
//   waits: vmcnt(4) ONLY at end-P4 and end-P8 (2 instr/stage/wave).
// Ledger (steady state, per wave): end-P4 outstanding =
//   {prevP7,prevP8,P1..P4} = 12 -> vmcnt(4) clears {prevP7,prevP8,P1,P2}
//   (= A/B(t+1)k0 needed P5-6, A/B(t+1)k1 needed P7-8), leaves {P3,P4}.
//   end-P8: {P3..P8}=12 -> clears {P3..P6} (= tile t+2, needed next
//   P1-P4), leaves {P7,P8}. Min leash = 2 phases (~1700 cyc > 900 HBM);
//   most 4-7 phases. Never vmcnt(0) in-loop.
// Buffer lifetimes: each (buf,kh) plane's reads finish >= 1 barrier
//   before its next stage-write issues; writes are vmcnt-cleared +
//   barrier-published >= 1 barrier before next read. (Checked per-phase.)
// Phase body: reads; stage; s_barrier; lgkmcnt(0)+sched_barrier;
//   setprio(1); 16 MFMA; setprio(0); [vmcnt(4)]; s_barrier.
// MODE 0: fused QKV epilogue (Q scaled 1/32); MODE 2: bf16 out, z-strided.
// Epilogue/frag math identical to R1/R2 (correctness-passed).
// ============================================================================

#define MM16(a, b, c) __builtin_amdgcn_mfma_f32_16x16x32_bf16(a, b, c, 0, 0, 0)

#define STAGE_A(BUF, KH, KT) do {                                            \
    gload_lds16(Asrc + (KT) + (KH) * 32,                                     \
                AsW + (BUF) * 16384 + (KH) * 8192);                          \
    gload_lds16(Asrc + (size_t)128 * lda + (KT) + (KH) * 32,                 \
                AsW + (BUF) * 16384 + (KH) * 8192 + 4096);                   \
  } while (0)
#define STAGE_B(BUF, KH, KT) do {                                            \
    gload_lds16(Bsrc + (KT) + (KH) * 32,                                     \
                BsW + (BUF) * 16384 + (KH) * 8192);                          \
    gload_lds16(Bsrc + (size_t)128 * ldb + (KT) + (KH) * 32,                 \
                BsW + (BUF) * 16384 + (KH) * 8192 + 4096);                   \
  } while (0)

#define APTR(BUF, MI, KS) \
  ((const bf16x8*)(ArdBase + (BUF) * 16384 + (KS) * 8192 + (MI) * 512))
#define BPTR(BUF, NI, KS) \
  ((const bf16x8*)(BrdBase + (BUF) * 16384 + (KS) * 8192 + (NI) * 512))

#define VM4   asm volatile("s_waitcnt vmcnt(4)" ::: "memory")
#define NOVM  (void)0

// one phase: 4 A-frags (+4 B-frags if RDB), 1 half-tile stage, barrier,
// counted-lgkm drain, 16 MFMA, optional vmcnt, barrier.
#define PH(BUF, MH, KS, RDB, STG, VMW) do {                                  \
    bf16x8 a0 = *APTR(BUF, (MH) * 4 + 0, KS);                                \
    bf16x8 a1 = *APTR(BUF, (MH) * 4 + 1, KS);                                \
    bf16x8 a2 = *APTR(BUF, (MH) * 4 + 2, KS);                                \
    bf16x8 a3 = *APTR(BUF, (MH) * 4 + 3, KS);                                \
    if (RDB) {                                                               \
      bf0 = *BPTR(BUF, 0, KS);                                               \
      bf1 = *BPTR(BUF, 1, KS);                                               \
      bf2 = *BPTR(BUF, 2, KS);                                               \
      bf3 = *BPTR(BUF, 3, KS);                                               \
    }                                                                        \
    STG;                                                                     \
    __builtin_amdgcn_s_barrier();                                            \
    asm volatile("s_waitcnt lgkmcnt(0)" ::: "memory");                       \
    __builtin_amdgcn_sched_barrier(0);                                       \
    __builtin_amdgcn_s_setprio(1);                                           \
    acc[(MH)*4+0][0] = MM16(a0, bf0, acc[(MH)*4+0][0]);                      \
    acc[(MH)*4+1][0] = MM16(a1, bf0, acc[(MH)*4+1][0]);                      \
    acc[(MH)*4+2][0] = MM16(a2, bf0, acc[(MH)*4+2][0]);                      \
    acc[(MH)*4+3][0] = MM16(a3, bf0, acc[(MH)*4+3][0]);                      \
    acc[(MH)*4+0][1] = MM16(a0, bf1, acc[(MH)*4+0][1]);                      \
    acc[(MH)*4+1][1] = MM16(a1, bf1, acc[(MH)*4+1][1]);                      \
    acc[(MH)*4+2][1] = MM16(a2, bf1, acc[(MH)*4+2][1]);                      \
    acc[(MH)*4+3][1] = MM16(a3, bf1, acc[(MH)*4+3][1]);                      \
    acc[(MH)*4+0][2] = MM16(a0, bf2, acc[(MH)*4+0][2]);                      \
    acc[(MH)*4+1][2] = MM16(a1, bf2, acc[(MH)*4+1][2]);                      \
    acc[(MH)*4+2][2] = MM16(a2, bf2, acc[(MH)*4+2][2]);                      \
    acc[(MH)*4+3][2] = MM16(a3, bf2, acc[(MH)*4+3][2]);                      \
    acc[(MH)*4+0][3] = MM16(a0, bf3, acc[(MH)*4+0][3]);                      \
    acc[(MH)*4+1][3] = MM16(a1, bf3, acc[(MH)*4+1][3]);                      \
    acc[(MH)*4+2][3] = MM16(a2, bf3, acc[(MH)*4+2][3]);                      \
    acc[(MH)*4+3][3] = MM16(a3, bf3, acc[(MH)*4+3][3]);                      \
    __builtin_amdgcn_s_setprio(0);                                           \
    VMW;                                                                     \
    __builtin_amdgcn_sched_barrier(0);                                       \
    __builtin_amdgcn_s_barrier();                                            \
  } while (0)

template<int MODE>
__global__ __launch_bounds__(512, 1)
void gemm8p(const u16* __restrict__ Ain, const u16* __restrict__ Bin,
            void* __restrict__ Cv,
            const float* __restrict__ b0, const float* __restrict__ b1,
            const float* __restrict__ b2,
            int lda, int ldb, int ldc, int K,
            unsigned long long sA, unsigned long long sB, unsigned long long sC,
            int nbx, int nby)
{
  __shared__ alignas(16) u16 As[2 * 2 * 256 * 32];   // 64 KiB
  __shared__ alignas(16) u16 Bs[2 * 2 * 256 * 32];   // 64 KiB

  // XCD-chunk + group-m swizzle (grid % 8 == 0 at all call sites)
  const int nbxy = nbx * nby;
  const int bid  = blockIdx.x;
  const int flat = (bid & 7) * ((int)gridDim.x >> 3) + (bid >> 3);
  const int z    = flat / nbxy;
  const int rr   = flat - z * nbxy;
  const int width = nbx << 3;
  const int gid  = rr / width;
  const int rw   = rr - gid * width;
  const int by   = (gid << 3) + (rw & 7);
  const int bx   = rw >> 3;

  const u16* A = Ain + z * sA;
  const u16* B = Bin + z * sB;

  const int tid  = threadIdx.x;
  const int wave = tid >> 6;
  const int lane = tid & 63;
  const int wr   = wave >> 2;     // 0..1  (m)
  const int wc   = wave & 3;      // 0..3  (n)
  const int l16  = lane & 15;
  const int l4   = lane >> 4;

  const int m0 = by << 8;
  const int n0 = bx << 8;

  // --- staging addresses (source carries the inverse 2-bit swizzle) ---
  const int gch = (tid & 3) ^ ((tid >> 3) & 3);
  const u16* Asrc = A + (size_t)(m0 + (tid >> 2)) * lda + gch * 8;
  const u16* Bsrc = B + (size_t)(n0 + (tid >> 2)) * ldb + gch * 8;
  u16* AsW = As + tid * 8;        // + buf*16384 + kh*8192 + c*4096
  u16* BsW = Bs + tid * 8;

  // --- fragment read bases (R5-class layout, 0 conflicts) ---
  const int rsw = (l4 ^ ((l16 >> 1) & 3)) << 3;
  const u16* ArdBase = As + (size_t)(wr * 128 + l16) * 32 + rsw;
  const u16* BrdBase = Bs + (size_t)(wc * 64 + l16) * 32 + rsw;

  f32x4 acc[8][4];
  #pragma unroll
  for (int i = 0; i < 8; ++i)
    #pragma unroll
    for (int j = 0; j < 4; ++j)
      #pragma unroll
      for (int r = 0; r < 4; ++r)
        acc[i][j][r] = 0.f;

  bf16x8 bf0, bf1, bf2, bf3;      // B-frags, reused across the mh pair

  // prologue: tile0 (both kh) + tile1 kh0; clear tile0, keep tile1-kh0 in flight.
  STAGE_A(0, 0, 0);  STAGE_B(0, 0, 0);
  STAGE_A(0, 1, 0);  STAGE_B(0, 1, 0);
  STAGE_A(1, 0, 64); STAGE_B(1, 0, 64);
  VM4;
  __builtin_amdgcn_sched_barrier(0);
  __builtin_amdgcn_s_barrier();

  const int NT = K >> 6;   // BK=64 tiles; NT even at all call sites
  for (int t = 0; t < NT; t += 2) {
    const int kt1 = (t + 1) * 64;
    const int kt2 = (t + 2 < NT) ? (t + 2) * 64 : 0;   // wrap: harmless re-stage
    const int kt3 = (t + 3 < NT) ? (t + 3) * 64 : 0;
    PH(0, 0, 0, 1, STAGE_A(1, 1, kt1), NOVM);
    PH(0, 1, 0, 0, STAGE_B(1, 1, kt1), NOVM);
    PH(0, 0, 1, 1, STAGE_A(0, 0, kt2), NOVM);
    PH(0, 1, 1, 0, STAGE_B(0, 0, kt2), VM4);
    PH(1, 0, 0, 1, STAGE_A(0, 1, kt2), NOVM);
    PH(1, 1, 0, 0, STAGE_B(0, 1, kt2), NOVM);
    PH(1, 0, 1, 1, STAGE_A(1, 0, kt3), NOVM);
    PH(1, 1, 1, 0, STAGE_B(1, 0, kt3), VM4);
  }
  asm volatile("s_waitcnt vmcnt(0)" ::: "memory");   // drain wrap stages

  // epilogue: C/D 16x16x32 map: col = lane&15, row = (lane>>4)*4 + reg (m89)
  if constexpr (MODE == 0) {
    const int g = n0 >> 10;                     // 0=Q, 1=K, 2=V (block-uniform)
    const int colb = (n0 + wc * 64) & 1023;
    const int rowb = m0 + wr * 128 + l4 * 4;
    if (g < 2) {
      u16* Cb = (u16*)Cv + (size_t)g * 8388608ULL;
      const float* bp = (g == 0) ? b0 : b1;
      const float qs = (g == 0) ? 0.03125f : 1.0f;   // fold 1/sqrt(1024) into Q
      #pragma unroll
      for (int ni = 0; ni < 4; ++ni) {
        const int col = colb + ni * 16 + l16;
        const float bv = bp[col];
        #pragma unroll
        for (int mi = 0; mi < 8; ++mi) {
          const int row = rowb + mi * 16;
          #pragma unroll
          for (int r = 0; r < 4; ++r)
            Cb[(size_t)(row + r) * 1024 + col] = f2bf((acc[mi][ni][r] + bv) * qs);
        }
      }
    } else {
      u16* Vt = (u16*)Cv + 16777216ULL;         // [4][1024][2048]
      #pragma unroll
      for (int ni = 0; ni < 4; ++ni) {
        const int col = colb + ni * 16 + l16;
        const float bv = b2[col];
        #pragma unroll
        for (int mi = 0; mi < 8; ++mi) {
          const int row = rowb + mi * 16;       // 4 consecutive s via reg idx
          u16x4 o;
          #pragma unroll
          for (int r = 0; r < 4; ++r) o[r] = f2bf(acc[mi][ni][r] + bv);
          const size_t idx = ((size_t)((row >> 11) * 1024 + col)) * 2048 + (row & 2047);
          *(u16x4*)&Vt[idx] = o;
        }
      }
    }
  } else {   // MODE 2: bf16 out, row-major ldc, z-strided
    u16* Cb = (u16*)Cv + (size_t)z * sC;
    #pragma unroll
    for (int ni = 0; ni < 4; ++ni) {
      const int col = n0 + wc * 64 + ni * 16 + l16;
      #pragma unroll
      for (int mi = 0; mi < 8; ++mi) {
        const int row = m0 + wr * 128 + mi * 16 + l4 * 4;
        #pragma unroll
        for (int r = 0; r < 4; ++r)
          Cb[(size_t)(row + r) * ldc + col] = f2bf(acc[mi][ni][r]);
      }
    }
  }
}

// ============================================================================
// legacy 128x128 2-phase kernel (round-0 proven) — kept for PV (512 blocks).
// ============================================================================
template<int MODE>
__global__ __launch_bounds__(256)
void gemm_bt(const u16* __restrict__ Ain, const u16* __restrict__ Bin,
             void* __restrict__ Cv,
             int lda, int ldb, int ldc, int K,
             unsigned long long sA, unsigned long long sB, unsigned long long sC,
             int nbx, int nby)
{
  constexpr int BM = 128, BK = 64;
  __shared__ alignas(16) u16 As[BM * BK];
  __shared__ alignas(16) u16 Bs[BM * BK];

  const int nbxy = nbx * nby;
  const int bid  = blockIdx.x;
  const int flat = (bid & 7) * ((int)gridDim.x >> 3) + (bid >> 3);
  const int z    = flat / nbxy;
  const int rr   = flat - z * nbxy;
  const int width = nbx << 3;
  const int gid  = rr / width;
  const int rw   = rr - gid * width;
  const int by   = (gid << 3) + (rw & 7);
  const int bx   = rw >> 3;

  const u16* A = Ain + z * sA;
  const u16* B = Bin + z * sB;

  const int tid  = threadIdx.x;
  const int wave = tid >> 6;
  const int lane = tid & 63;
  const int l32  = lane & 31;
  const int half = lane >> 5;
  const int wr   = wave >> 1;
  const int wc   = wave & 1;

  const int m0 = by * BM;
  const int n0 = bx * BM;

  const int lr = lane >> 3;
  const int sc = ((lane & 7) ^ lr) * 8;
  const u16* Ag = A + (size_t)(m0 + wave * 32 + lr) * lda + sc;
  const u16* Bg = B + (size_t)(n0 + wave * 32 + lr) * ldb + sc;
  u16* Asb = &As[(wave * 32) * BK];
  u16* Bsb = &Bs[(wave * 32) * BK];

  f32x16 acc[2][2];
  #pragma unroll
  for (int i = 0; i < 2; ++i)
    #pragma unroll
    for (int j = 0; j < 2; ++j)
      #pragma unroll
      for (int r = 0; r < 16; ++r)
        acc[i][j][r] = 0.f;

  for (int k0 = 0; k0 < K; k0 += BK) {
    gload_lds16(Ag + k0,                    Asb);
    gload_lds16(Ag + (size_t) 8 * lda + k0, Asb +  8 * BK);
    gload_lds16(Ag + (size_t)16 * lda + k0, Asb + 16 * BK);
    gload_lds16(Ag + (size_t)24 * lda + k0, Asb + 24 * BK);
    gload_lds16(Bg + k0,                    Bsb);
    gload_lds16(Bg + (size_t) 8 * ldb + k0, Bsb +  8 * BK);
    gload_lds16(Bg + (size_t)16 * ldb + k0, Bsb + 16 * BK);
    gload_lds16(Bg + (size_t)24 * ldb + k0, Bsb + 24 * BK);
    __syncthreads();

    #pragma unroll
    for (int ks = 0; ks < 4; ++ks) {
      bf16x8 af[2], bfr[2];
      #pragma unroll
      for (int ti = 0; ti < 2; ++ti) {
        const int row = wr * 64 + ti * 32 + l32;
        const int ch  = ((ks * 2 + half) ^ (row & 7)) * 8;
        af[ti] = *(const bf16x8*)&As[row * BK + ch];
      }
      #pragma unroll
      for (int tj = 0; tj < 2; ++tj) {
        const int row = wc * 64 + tj * 32 + l32;
        const int ch  = ((ks * 2 + half) ^ (row & 7)) * 8;
        bfr[tj] = *(const bf16x8*)&Bs[row * BK + ch];
      }
      #pragma unroll
      for (int ti = 0; ti < 2; ++ti)
        #pragma unroll
        for (int tj = 0; tj < 2; ++tj)
          acc[ti][tj] = __builtin_amdgcn_mfma_f32_32x32x16_bf16(af[ti], bfr[tj], acc[ti][tj], 0, 0, 0);
    }
    __syncthreads();
  }

  const int colb = n0 + wc * 64 + l32;
  const int rowb = m0 + wr * 64 + 4 * half;

  if constexpr (MODE == 3) {
    float* Cf = (float*)Cv + z * sC;
    #pragma unroll
    for (int tj = 0; tj < 2; ++tj) {
      const int col = colb + tj * 32;
      #pragma unroll
      for (int ti = 0; ti < 2; ++ti)
        #pragma unroll
        for (int g4 = 0; g4 < 4; ++g4)
          #pragma unroll
          for (int r = 0; r < 4; ++r) {
            const int row = rowb + ti * 32 + g4 * 8 + r;
            Cf[(size_t)row * ldc + col] = acc[ti][tj][g4 * 4 + r];
          }
    }
  }
}

// one block per row; reads bf16 logits, writes fp32 attn to d_out and
// bf16 attn in-place (input to the PV gemm).
__global__ __launch_bounds__(256)
void softmax_rows(u16* __restrict__ logits, float* __restrict__ attn) {
  const int row = blockIdx.x;
  const int tid = threadIdx.x;
  u16*   lp = logits + (size_t)row * 2048 + tid * 8;
  float* ap = attn   + (size_t)row * 2048 + tid * 8;

  u16x8 raw = *(const u16x8*)lp;
  float v[8];
  #pragma unroll
  for (int j = 0; j < 8; ++j) v[j] = bf2f(raw[j]);

  float mx = v[0];
  #pragma unroll
  for (int j = 1; j < 8; ++j) mx = fmaxf(mx, v[j]);
  #pragma unroll
  for (int o = 32; o > 0; o >>= 1) mx = fmaxf(mx, __shfl_xor(mx, o, 64));

  __shared__ float smax[4], ssum[4];
  const int wv = tid >> 6, ln = tid & 63;
  if (ln == 0) smax[wv] = mx;
  __syncthreads();
  mx = fmaxf(fmaxf(smax[0], smax[1]), fmaxf(smax[2], smax[3]));

  float s = 0.f;
  #pragma unroll
  for (int j = 0; j < 8; ++j) { v[j] = __expf(v[j] - mx); s += v[j]; }
  #pragma unroll
  for (int o = 32; o > 0; o >>= 1) s += __shfl_xor(s, o, 64);
  if (ln == 0) ssum[wv] = s;
  __syncthreads();
  s = (ssum[0] + ssum[1]) + (ssum[2] + ssum[3]);
  const float inv = 1.f / s;

  u16x8 ob;
  #pragma unroll
  for (int j = 0; j < 8; ++j) { v[j] *= inv; ob[j] = f2bf(v[j]); }
  float4* apv = (float4*)ap;
  apv[0] = make_float4(v[0], v[1], v[2], v[3]);
  apv[1] = make_float4(v[4], v[5], v[6], v[7]);
  *(u16x8*)lp = ob;
}

extern "C" void kernel_launch(void* const* d_in, const int* in_sizes, int n_in,
                              void* d_out, int out_size, void* d_ws, size_t ws_size,
                              hipStream_t stream) {
  (void)in_sizes; (void)n_in; (void)out_size; (void)ws_size;
  const float* x    = (const float*)d_in[0];
  const float* wq_w = (const float*)d_in[1];
  const float* wq_b = (const float*)d_in[2];
  const float* wk_w = (const float*)d_in[3];
  const float* wk_b = (const float*)d_in[4];
  const float* wv_w = (const float*)d_in[5];
  const float* wv_b = (const float*)d_in[6];

  float* attn = (float*)d_out;                 // [4,2048,2048] fp32
  float* outp = attn + 16777216ULL;            // [4,2048,1024] fp32

  // ws layout (u16 elems): x_bf(8M) | wcat(3M) | Q(8M) | K(8M) | V^T(8M) | logits(16M)
  u16* xb   = (u16*)d_ws;
  u16* wcat = xb   + 8388608ULL;
  u16* Qb   = wcat + 3145728ULL;   // [8192][1024], pre-scaled by 1/32
  u16* Kb   = Qb   + 8388608ULL;   // [8192][1024]
  u16* Vt   = Kb   + 8388608ULL;   // [4][1024][2048]
  u16* Lg   = Vt   + 8388608ULL;   // [4][2048][2048]

  cvt_f32_bf16<<<8192, 256, 0, stream>>>(x, xb);
  cvt_w3<<<3072, 256, 0, stream>>>(wq_w, wk_w, wv_w, wcat);

  // fused QKV: M=8192, N=3072, K=1024  (256^2 tiles -> 32x12 = 384 blocks)
  gemm8p<0><<<384, 512, 0, stream>>>(xb, wcat, Qb, wq_b, wk_b, wv_b,
                                     1024, 1024, 1024, 1024, 0, 0, 0, 12, 32);

  // logits = (Q/32) K^T per batch: M=N=2048, K=1024  (8x8x4 = 256 blocks)
  gemm8p<2><<<256, 512, 0, stream>>>(Qb, Kb, Lg, nullptr, nullptr, nullptr,
                                     1024, 1024, 2048, 1024,
                                     2097152ULL, 2097152ULL, 4194304ULL, 8, 8);

  softmax_rows<<<8192, 256, 0, stream>>>(Lg, attn);

  // out = attn V: M=2048, N=1024, K=2048 per batch (legacy 128^2, 512 blocks)
  gemm_bt<3><<<512, 256, 0, stream>>>(Lg, Vt, outp,
                                      2048, 2048, 1024, 2048,
                                      4194304ULL, 2097152ULL, 2097152ULL, 8, 16);
}

// Round 7
// 312.061 us; speedup vs baseline: 1.0730x; 1.0067x over previous
//
#include <hip/hip_runtime.h>

typedef unsigned short u16;
typedef u16 u16x4 __attribute__((ext_vector_type(4)));
typedef u16 u16x8 __attribute__((ext_vector_type(8)));
typedef __bf16 bf16x8 __attribute__((ext_vector_type(8)));
typedef float f32x4 __attribute__((ext_vector_type(4)));
typedef float f32x16 __attribute__((ext_vector_type(16)));

static __device__ __forceinline__ u16 f2bf(float f) {
  unsigned u = __builtin_bit_cast(unsigned, f);
  u += 0x7fffu + ((u >> 16) & 1u);   // RNE; finite inputs
  return (u16)(u >> 16);
}
static __device__ __forceinline__ float bf2f(u16 h) {
  return __builtin_bit_cast(float, ((unsigned)h) << 16);
}

// async global->LDS, 16B/lane. LDS dest = wave-uniform base + lane*16.
static __device__ __forceinline__ void gload_lds16(const u16* g, u16* l) {
  u16* gn = const_cast<u16*>(g);
  __builtin_amdgcn_global_load_lds(
      (__attribute__((address_space(1))) unsigned int*)gn,
      (__attribute__((address_space(3))) unsigned int*)l,
      16, 0, 0);
}

// fused input conversions: blocks [0,8192) convert x (fp32->bf16, 8M elems);
// blocks [8192,11264) convert the three weight matrices into wcat.
__global__ __launch_bounds__(256)
void cvt_all(const float* __restrict__ x, u16* __restrict__ xb,
             const float* __restrict__ a, const float* __restrict__ b,
             const float* __restrict__ c, u16* __restrict__ wcat) {
  const int blkid = blockIdx.x;
  if (blkid < 8192) {
    const int i = blkid * 256 + threadIdx.x;
    float4 f = ((const float4*)x)[i];
    u16x4 o = { f2bf(f.x), f2bf(f.y), f2bf(f.z), f2bf(f.w) };
    ((u16x4*)xb)[i] = o;
  } else {
    const int blk = blkid - 8192;     // 0..3071
    const int w = blk >> 10;
    const float* src = (w == 0) ? a : (w == 1) ? b : c;
    const int i = (blk & 1023) * 256 + threadIdx.x;
    float4 f = ((const float4*)src)[i];
    u16x4 o = { f2bf(f.x), f2bf(f.y), f2bf(f.z), f2bf(f.w) };
    ((u16x4*)(wcat + (size_t)w * 1048576ULL))[i] = o;
  }
}

// ============================================================================
// R0-proven legacy 128x128 GEMM. C[m][n] = sum_k A[m][k]*B[n][k].
// mfma_f32_32x32x16_bf16; 4 waves (2x2), wave tile 64x64 = 2x2 of 32x32.
// Single-buffer BK=64; stage -> sync -> compute -> sync. 32 KiB LDS,
// VGPR 92 -> ~5 blocks/CU: cross-block overlap hides the stage drain.
// A/B frag: [row=lane&31][k = kstep*16 + (lane>>5)*8 + j]
// C/D frag (m74/m101): col=lane&31, row=(reg&3)+8*(reg>>2)+4*(lane>>5)
// LDS XOR swizzle: LDS(row,c) holds global chunk c^(row&7) (16B chunks).
// MODE 0: fused QKV epilogue; Q scaled by 1/32 (folded logit scale).
// MODE 3: fp32 out, row-major ldc, z-strided   (attn @ V^T)
// ============================================================================
template<int MODE>
__global__ __launch_bounds__(256)
void gemm_bt(const u16* __restrict__ Ain, const u16* __restrict__ Bin,
             void* __restrict__ Cv,
             const float* __restrict__ b0, const float* __restrict__ b1,
             const float* __restrict__ b2,
             int lda, int ldb, int ldc, int K,
             unsigned long long sA, unsigned long long sB, unsigned long long sC,
             int nbx, int nby)
{
  constexpr int BM = 128, BN = 128, BK = 64;
  __shared__ alignas(16) u16 As[BM * BK];
  __shared__ alignas(16) u16 Bs[BN * BK];

  // XCD-chunk + group-m swizzle
  const int nbxy = nbx * nby;
  const int bid  = blockIdx.x;
  const int flat = (bid & 7) * ((int)gridDim.x >> 3) + (bid >> 3);
  const int z    = flat / nbxy;
  const int rr   = flat - z * nbxy;
  const int width = nbx << 3;
  const int gid  = rr / width;
  const int rw   = rr - gid * width;
  const int by   = (gid << 3) + (rw & 7);
  const int bx   = rw >> 3;

  const u16* A = Ain + z * sA;
  const u16* B = Bin + z * sB;

  const int tid  = threadIdx.x;
  const int wave = tid >> 6;
  const int lane = tid & 63;
  const int l32  = lane & 31;
  const int half = lane >> 5;
  const int wr   = wave >> 1;     // 2x2 wave grid, 64x64 per wave
  const int wc   = wave & 1;

  const int m0 = by * BM;
  const int n0 = bx * BN;

  // staging: 64 lanes cover 8 rows x 8 chunks(16B) per instruction
  const int lr = lane >> 3;
  const int sc = ((lane & 7) ^ lr) * 8;     // swizzled global chunk
  const u16* Ag = A + (size_t)(m0 + wave * 32 + lr) * lda + sc;
  const u16* Bg = B + (size_t)(n0 + wave * 32 + lr) * ldb + sc;
  u16* Asb = &As[(wave * 32) * BK];
  u16* Bsb = &Bs[(wave * 32) * BK];

  f32x16 acc[2][2];
  #pragma unroll
  for (int i = 0; i < 2; ++i)
    #pragma unroll
    for (int j = 0; j < 2; ++j)
      #pragma unroll
      for (int r = 0; r < 16; ++r)
        acc[i][j][r] = 0.f;

  for (int k0 = 0; k0 < K; k0 += BK) {
    gload_lds16(Ag + k0,                    Asb);
    gload_lds16(Ag + (size_t) 8 * lda + k0, Asb +  8 * BK);
    gload_lds16(Ag + (size_t)16 * lda + k0, Asb + 16 * BK);
    gload_lds16(Ag + (size_t)24 * lda + k0, Asb + 24 * BK);
    gload_lds16(Bg + k0,                    Bsb);
    gload_lds16(Bg + (size_t) 8 * ldb + k0, Bsb +  8 * BK);
    gload_lds16(Bg + (size_t)16 * ldb + k0, Bsb + 16 * BK);
    gload_lds16(Bg + (size_t)24 * ldb + k0, Bsb + 24 * BK);
    __syncthreads();

    #pragma unroll
    for (int ks = 0; ks < 4; ++ks) {
      bf16x8 af[2], bfr[2];
      #pragma unroll
      for (int ti = 0; ti < 2; ++ti) {
        const int row = wr * 64 + ti * 32 + l32;
        const int ch  = ((ks * 2 + half) ^ (row & 7)) * 8;
        af[ti] = *(const bf16x8*)&As[row * BK + ch];
      }
      #pragma unroll
      for (int tj = 0; tj < 2; ++tj) {
        const int row = wc * 64 + tj * 32 + l32;
        const int ch  = ((ks * 2 + half) ^ (row & 7)) * 8;
        bfr[tj] = *(const bf16x8*)&Bs[row * BK + ch];
      }
      #pragma unroll
      for (int ti = 0; ti < 2; ++ti)
        #pragma unroll
        for (int tj = 0; tj < 2; ++tj)
          acc[ti][tj] = __builtin_amdgcn_mfma_f32_32x32x16_bf16(af[ti], bfr[tj], acc[ti][tj], 0, 0, 0);
    }
    __syncthreads();
  }

  // epilogue lane mapping
  const int colb = n0 + wc * 64 + l32;          // + tj*32
  const int rowb = m0 + wr * 64 + 4 * half;     // + ti*32 + (reg&3) + 8*(reg>>2)

  if constexpr (MODE == 0) {
    const int g = n0 >> 10;                     // 0=Q, 1=K, 2=V (block-uniform)
    u16* Qb = (u16*)Cv;
    if (g < 2) {
      u16* Cb = Qb + (size_t)g * 8388608ULL;
      const float* bp = (g == 0) ? b0 : b1;
      const float qs = (g == 0) ? 0.03125f : 1.0f;   // fold 1/sqrt(1024) into Q
      #pragma unroll
      for (int tj = 0; tj < 2; ++tj) {
        const int col = (colb + tj * 32) & 1023;
        const float bv = bp[col];
        #pragma unroll
        for (int ti = 0; ti < 2; ++ti)
          #pragma unroll
          for (int g4 = 0; g4 < 4; ++g4)
            #pragma unroll
            for (int r = 0; r < 4; ++r) {
              const int row = rowb + ti * 32 + g4 * 8 + r;
              Cb[(size_t)row * 1024 + col] = f2bf((acc[ti][tj][g4 * 4 + r] + bv) * qs);
            }
      }
    } else {
      u16* Vt = Qb + 16777216ULL;               // [4][1024][2048]
      #pragma unroll
      for (int tj = 0; tj < 2; ++tj) {
        const int col = (colb + tj * 32) & 1023;
        const float bv = b2[col];
        #pragma unroll
        for (int ti = 0; ti < 2; ++ti)
          #pragma unroll
          for (int g4 = 0; g4 < 4; ++g4) {
            const int row = rowb + ti * 32 + g4 * 8;   // 4 consecutive s
            u16x4 o;
            #pragma unroll
            for (int r = 0; r < 4; ++r) o[r] = f2bf(acc[ti][tj][g4 * 4 + r] + bv);
            const size_t idx = ((size_t)((row >> 11) * 1024 + col)) * 2048 + (row & 2047);
            *(u16x4*)&Vt[idx] = o;
          }
      }
    }
  } else {   // MODE 3: fp32 out, row-major ldc, z-strided
    float* Cf = (float*)Cv + z * sC;
    #pragma unroll
    for (int tj = 0; tj < 2; ++tj) {
      const int col = colb + tj * 32;
      #pragma unroll
      for (int ti = 0; ti < 2; ++ti)
        #pragma unroll
        for (int g4 = 0; g4 < 4; ++g4)
          #pragma unroll
          for (int r = 0; r < 4; ++r) {
            const int row = rowb + ti * 32 + g4 * 8 + r;
            Cf[(size_t)row * ldc + col] = acc[ti][tj][g4 * 4 + r];
          }
    }
  }
}

// ============================================================================
// R6-proven 256x256 8-phase GEMM — used ONLY where the grid packs the
// machine exactly (logits: 8x8x4 = 256 blocks = 1.0 dispatch waves at
// 1 block/CU). 512 thr = 8 waves (2m x 4n); per-wave 128x64 out via
// mfma_f32_16x16x32_bf16. BK=64 as two k-halves; LDS 128 KiB dbuf.
// Stage order P1..P8: A(t+1)k1 B(t+1)k1 A(t+2)k0 B(t+2)k0 A(t+2)k1
//   B(t+2)k1 A(t+3)k0 B(t+3)k0; vmcnt(4) only at end-P4/P8 (min leash
//   2 phases > HBM latency). 0 bank conflicts (R5-class layout).
// ============================================================================

#define MM16(a, b, c) __builtin_amdgcn_mfma_f32_16x16x32_bf16(a, b, c, 0, 0, 0)

#define STAGE_A(BUF, KH, KT) do {                                            \
    gload_lds16(Asrc + (KT) + (KH) * 32,                                     \
                AsW + (BUF) * 16384 + (KH) * 8192);                          \
    gload_lds16(Asrc + (size_t)128 * lda + (KT) + (KH) * 32,                 \
                AsW + (BUF) * 16384 + (KH) * 8192 + 4096);                   \
  } while (0)
#define STAGE_B(BUF, KH, KT) do {                                            \
    gload_lds16(Bsrc + (KT) + (KH) * 32,                                     \
                BsW + (BUF) * 16384 + (KH) * 8192);                          \
    gload_lds16(Bsrc + (size_t)128 * ldb + (KT) + (KH) * 32,                 \
                BsW + (BUF) * 16384 + (KH) * 8192 + 4096);                   \
  } while (0)

#define APTR(BUF, MI, KS) \
  ((const bf16x8*)(ArdBase + (BUF) * 16384 + (KS) * 8192 + (MI) * 512))
#define BPTR(BUF, NI, KS) \
  ((const bf16x8*)(BrdBase + (BUF) * 16384 + (KS) * 8192 + (NI) * 512))

#define VM4   asm volatile("s_waitcnt vmcnt(4)" ::: "memory")
#define NOVM  (void)0

#define PH(BUF, MH, KS, RDB, STG, VMW) do {                                  \
    bf16x8 a0 = *APTR(BUF, (MH) * 4 + 0, KS);                                \
    bf16x8 a1 = *APTR(BUF, (MH) * 4 + 1, KS);                                \
    bf16x8 a2 = *APTR(BUF, (MH) * 4 + 2, KS);                                \
    bf16x8 a3 = *APTR(BUF, (MH) * 4 + 3, KS);                                \
    if (RDB) {                                                               \
      bf0 = *BPTR(BUF, 0, KS);                                               \
      bf1 = *BPTR(BUF, 1, KS);                                               \
      bf2 = *BPTR(BUF, 2, KS);                                               \
      bf3 = *BPTR(BUF, 3, KS);                                               \
    }                                                                        \
    STG;                                                                     \
    __builtin_amdgcn_s_barrier();                                            \
    asm volatile("s_waitcnt lgkmcnt(0)" ::: "memory");                       \
    __builtin_amdgcn_sched_barrier(0);                                       \
    __builtin_amdgcn_s_setprio(1);                                           \
    acc[(MH)*4+0][0] = MM16(a0, bf0, acc[(MH)*4+0][0]);                      \
    acc[(MH)*4+1][0] = MM16(a1, bf0, acc[(MH)*4+1][0]);                      \
    acc[(MH)*4+2][0] = MM16(a2, bf0, acc[(MH)*4+2][0]);                      \
    acc[(MH)*4+3][0] = MM16(a3, bf0, acc[(MH)*4+3][0]);                      \
    acc[(MH)*4+0][1] = MM16(a0, bf1, acc[(MH)*4+0][1]);                      \
    acc[(MH)*4+1][1] = MM16(a1, bf1, acc[(MH)*4+1][1]);                      \
    acc[(MH)*4+2][1] = MM16(a2, bf1, acc[(MH)*4+2][1]);                      \
    acc[(MH)*4+3][1] = MM16(a3, bf1, acc[(MH)*4+3][1]);                      \
    acc[(MH)*4+0][2] = MM16(a0, bf2, acc[(MH)*4+0][2]);                      \
    acc[(MH)*4+1][2] = MM16(a1, bf2, acc[(MH)*4+1][2]);                      \
    acc[(MH)*4+2][2] = MM16(a2, bf2, acc[(MH)*4+2][2]);                      \
    acc[(MH)*4+3][2] = MM16(a3, bf2, acc[(MH)*4+3][2]);                      \
    acc[(MH)*4+0][3] = MM16(a0, bf3, acc[(MH)*4+0][3]);                      \
    acc[(MH)*4+1][3] = MM16(a1, bf3, acc[(MH)*4+1][3]);                      \
    acc[(MH)*4+2][3] = MM16(a2, bf3, acc[(MH)*4+2][3]);                      \
    acc[(MH)*4+3][3] = MM16(a3, bf3, acc[(MH)*4+3][3]);                      \
    __builtin_amdgcn_s_setprio(0);                                           \
    VMW;                                                                     \
    __builtin_amdgcn_sched_barrier(0);                                       \
    __builtin_amdgcn_s_barrier();                                            \
  } while (0)

template<int MODE>
__global__ __launch_bounds__(512, 1)
void gemm8p(const u16* __restrict__ Ain, const u16* __restrict__ Bin,
            void* __restrict__ Cv,
            int lda, int ldb, int ldc, int K,
            unsigned long long sA, unsigned long long sB, unsigned long long sC,
            int nbx, int nby)
{
  __shared__ alignas(16) u16 As[2 * 2 * 256 * 32];   // 64 KiB
  __shared__ alignas(16) u16 Bs[2 * 2 * 256 * 32];   // 64 KiB

  const int nbxy = nbx * nby;
  const int bid  = blockIdx.x;
  const int flat = (bid & 7) * ((int)gridDim.x >> 3) + (bid >> 3);
  const int z    = flat / nbxy;
  const int rr   = flat - z * nbxy;
  const int width = nbx << 3;
  const int gid  = rr / width;
  const int rw   = rr - gid * width;
  const int by   = (gid << 3) + (rw & 7);
  const int bx   = rw >> 3;

  const u16* A = Ain + z * sA;
  const u16* B = Bin + z * sB;

  const int tid  = threadIdx.x;
  const int wave = tid >> 6;
  const int lane = tid & 63;
  const int wr   = wave >> 2;     // 0..1  (m)
  const int wc   = wave & 3;      // 0..3  (n)
  const int l16  = lane & 15;
  const int l4   = lane >> 4;

  const int m0 = by << 8;
  const int n0 = bx << 8;

  const int gch = (tid & 3) ^ ((tid >> 3) & 3);
  const u16* Asrc = A + (size_t)(m0 + (tid >> 2)) * lda + gch * 8;
  const u16* Bsrc = B + (size_t)(n0 + (tid >> 2)) * ldb + gch * 8;
  u16* AsW = As + tid * 8;        // + buf*16384 + kh*8192 + c*4096
  u16* BsW = Bs + tid * 8;

  const int rsw = (l4 ^ ((l16 >> 1) & 3)) << 3;
  const u16* ArdBase = As + (size_t)(wr * 128 + l16) * 32 + rsw;
  const u16* BrdBase = Bs + (size_t)(wc * 64 + l16) * 32 + rsw;

  f32x4 acc[8][4];
  #pragma unroll
  for (int i = 0; i < 8; ++i)
    #pragma unroll
    for (int j = 0; j < 4; ++j)
      #pragma unroll
      for (int r = 0; r < 4; ++r)
        acc[i][j][r] = 0.f;

  bf16x8 bf0, bf1, bf2, bf3;      // B-frags, reused across the mh pair

  STAGE_A(0, 0, 0);  STAGE_B(0, 0, 0);
  STAGE_A(0, 1, 0);  STAGE_B(0, 1, 0);
  STAGE_A(1, 0, 64); STAGE_B(1, 0, 64);
  VM4;
  __builtin_amdgcn_sched_barrier(0);
  __builtin_amdgcn_s_barrier();

  const int NT = K >> 6;   // BK=64 tiles; NT even at all call sites
  for (int t = 0; t < NT; t += 2) {
    const int kt1 = (t + 1) * 64;
    const int kt2 = (t + 2 < NT) ? (t + 2) * 64 : 0;   // wrap: harmless re-stage
    const int kt3 = (t + 3 < NT) ? (t + 3) * 64 : 0;
    PH(0, 0, 0, 1, STAGE_A(1, 1, kt1), NOVM);
    PH(0, 1, 0, 0, STAGE_B(1, 1, kt1), NOVM);
    PH(0, 0, 1, 1, STAGE_A(0, 0, kt2), NOVM);
    PH(0, 1, 1, 0, STAGE_B(0, 0, kt2), VM4);
    PH(1, 0, 0, 1, STAGE_A(0, 1, kt2), NOVM);
    PH(1, 1, 0, 0, STAGE_B(0, 1, kt2), NOVM);
    PH(1, 0, 1, 1, STAGE_A(1, 0, kt3), NOVM);
    PH(1, 1, 1, 0, STAGE_B(1, 0, kt3), VM4);
  }
  asm volatile("s_waitcnt vmcnt(0)" ::: "memory");   // drain wrap stages

  // MODE 2: bf16 out, row-major ldc, z-strided
  u16* Cb = (u16*)Cv + (size_t)z * sC;
  #pragma unroll
  for (int ni = 0; ni < 4; ++ni) {
    const int col = n0 + wc * 64 + ni * 16 + l16;
    #pragma unroll
    for (int mi = 0; mi < 8; ++mi) {
      const int row = m0 + wr * 128 + mi * 16 + l4 * 4;
      #pragma unroll
      for (int r = 0; r < 4; ++r)
        Cb[(size_t)(row + r) * ldc + col] = f2bf(acc[mi][ni][r]);
    }
  }
}

// one block per row; reads bf16 logits, writes fp32 attn to d_out and
// bf16 attn in-place (input to the PV gemm).
__global__ __launch_bounds__(256)
void softmax_rows(u16* __restrict__ logits, float* __restrict__ attn) {
  const int row = blockIdx.x;
  const int tid = threadIdx.x;
  u16*   lp = logits + (size_t)row * 2048 + tid * 8;
  float* ap = attn   + (size_t)row * 2048 + tid * 8;

  u16x8 raw = *(const u16x8*)lp;
  float v[8];
  #pragma unroll
  for (int j = 0; j < 8; ++j) v[j] = bf2f(raw[j]);

  float mx = v[0];
  #pragma unroll
  for (int j = 1; j < 8; ++j) mx = fmaxf(mx, v[j]);
  #pragma unroll
  for (int o = 32; o > 0; o >>= 1) mx = fmaxf(mx, __shfl_xor(mx, o, 64));

  __shared__ float smax[4], ssum[4];
  const int wv = tid >> 6, ln = tid & 63;
  if (ln == 0) smax[wv] = mx;
  __syncthreads();
  mx = fmaxf(fmaxf(smax[0], smax[1]), fmaxf(smax[2], smax[3]));

  float s = 0.f;
  #pragma unroll
  for (int j = 0; j < 8; ++j) { v[j] = __expf(v[j] - mx); s += v[j]; }
  #pragma unroll
  for (int o = 32; o > 0; o >>= 1) s += __shfl_xor(s, o, 64);
  if (ln == 0) ssum[wv] = s;
  __syncthreads();
  s = (ssum[0] + ssum[1]) + (ssum[2] + ssum[3]);
  const float inv = 1.f / s;

  u16x8 ob;
  #pragma unroll
  for (int j = 0; j < 8; ++j) { v[j] *= inv; ob[j] = f2bf(v[j]); }
  float4* apv = (float4*)ap;
  apv[0] = make_float4(v[0], v[1], v[2], v[3]);
  apv[1] = make_float4(v[4], v[5], v[6], v[7]);
  *(u16x8*)lp = ob;
}

extern "C" void kernel_launch(void* const* d_in, const int* in_sizes, int n_in,
                              void* d_out, int out_size, void* d_ws, size_t ws_size,
                              hipStream_t stream) {
  (void)in_sizes; (void)n_in; (void)out_size; (void)ws_size;
  const float* x    = (const float*)d_in[0];
  const float* wq_w = (const float*)d_in[1];
  const float* wq_b = (const float*)d_in[2];
  const float* wk_w = (const float*)d_in[3];
  const float* wk_b = (const float*)d_in[4];
  const float* wv_w = (const float*)d_in[5];
  const float* wv_b = (const float*)d_in[6];

  float* attn = (float*)d_out;                 // [4,2048,2048] fp32
  float* outp = attn + 16777216ULL;            // [4,2048,1024] fp32

  // ws layout (u16 elems): x_bf(8M) | wcat(3M) | Q(8M) | K(8M) | V^T(8M) | logits(16M)
  u16* xb   = (u16*)d_ws;
  u16* wcat = xb   + 8388608ULL;
  u16* Qb   = wcat + 3145728ULL;   // [8192][1024], pre-scaled by 1/32
  u16* Kb   = Qb   + 8388608ULL;   // [8192][1024]
  u16* Vt   = Kb   + 8388608ULL;   // [4][1024][2048]
  u16* Lg   = Vt   + 8388608ULL;   // [4][2048][2048]

  // fused conversions: one launch for x + all three weights
  cvt_all<<<11264, 256, 0, stream>>>(x, xb, wq_w, wk_w, wv_w, wcat);

  // fused QKV: M=8192, N=3072, K=1024 (legacy 128^2: 1536 blocks, ~5/CU)
  gemm_bt<0><<<1536, 256, 0, stream>>>(xb, wcat, Qb, wq_b, wk_b, wv_b,
                                       1024, 1024, 1024, 1024, 0, 0, 0, 24, 64);

  // logits = (Q/32) K^T per batch: M=N=2048, K=1024
  // (8-phase 256^2: 8x8x4 = 256 blocks = EXACTLY 1 block/CU machine-wide)
  gemm8p<2><<<256, 512, 0, stream>>>(Qb, Kb, Lg,
                                     1024, 1024, 2048, 1024,
                                     2097152ULL, 2097152ULL, 4194304ULL, 8, 8);

  softmax_rows<<<8192, 256, 0, stream>>>(Lg, attn);

  // out = attn V: M=2048, N=1024, K=2048 per batch (legacy 128^2, 512 blocks)
  gemm_bt<3><<<512, 256, 0, stream>>>(Lg, Vt, outp, nullptr, nullptr, nullptr,
                                      2048, 2048, 1024, 2048,
                                      4194304ULL, 2097152ULL, 2097152ULL, 8, 16);
}

// Round 8
// 310.688 us; speedup vs baseline: 1.0778x; 1.0044x over previous
//
#include <hip/hip_runtime.h>

typedef unsigned short u16;
typedef u16 u16x4 __attribute__((ext_vector_type(4)));
typedef u16 u16x8 __attribute__((ext_vector_type(8)));
typedef __bf16 bf16x8 __attribute__((ext_vector_type(8)));
typedef float f32x16 __attribute__((ext_vector_type(16)));

static __device__ __forceinline__ u16 f2bf(float f) {
  unsigned u = __builtin_bit_cast(unsigned, f);
  u += 0x7fffu + ((u >> 16) & 1u);   // RNE; finite inputs
  return (u16)(u >> 16);
}
static __device__ __forceinline__ float bf2f(u16 h) {
  return __builtin_bit_cast(float, ((unsigned)h) << 16);
}

// async global->LDS, 16B/lane. LDS dest = wave-uniform base + lane*16.
static __device__ __forceinline__ void gload_lds16(const u16* g, u16* l) {
  u16* gn = const_cast<u16*>(g);
  __builtin_amdgcn_global_load_lds(
      (__attribute__((address_space(1))) unsigned int*)gn,
      (__attribute__((address_space(3))) unsigned int*)l,
      16, 0, 0);
}

// fused input conversions (R7-validated): blocks [0,8192) convert x
// (fp32->bf16, 8M elems); blocks [8192,11264) convert the three weight
// matrices into wcat. One dispatch instead of two.
__global__ __launch_bounds__(256)
void cvt_all(const float* __restrict__ x, u16* __restrict__ xb,
             const float* __restrict__ a, const float* __restrict__ b,
             const float* __restrict__ c, u16* __restrict__ wcat) {
  const int blkid = blockIdx.x;
  if (blkid < 8192) {
    const int i = blkid * 256 + threadIdx.x;
    float4 f = ((const float4*)x)[i];
    u16x4 o = { f2bf(f.x), f2bf(f.y), f2bf(f.z), f2bf(f.w) };
    ((u16x4*)xb)[i] = o;
  } else {
    const int blk = blkid - 8192;     // 0..3071
    const int w = blk >> 10;
    const float* src = (w == 0) ? a : (w == 1) ? b : c;
    const int i = (blk & 1023) * 256 + threadIdx.x;
    float4 f = ((const float4*)src)[i];
    u16x4 o = { f2bf(f.x), f2bf(f.y), f2bf(f.z), f2bf(f.w) };
    ((u16x4*)(wcat + (size_t)w * 1048576ULL))[i] = o;
  }
}

// ============================================================================
// R0-proven 128x128 GEMM (best-measured artifact: 305.3/311.5 us pipelines).
// C[m][n] = sum_k A[m][k]*B[n][k], k-contiguous. BM=BN=128, BK=64.
// mfma_f32_32x32x16_bf16; 4 waves (2x2), wave tile 64x64 = 2x2 of 32x32.
// Single-buffer: stage -> sync -> compute -> sync; 32 KiB LDS, VGPR 92 ->
// multi-block residency provides the cross-block overlap that hides the
// stage drain (m114). SINGLE-VARIANT BUILD: no other GEMM kernel in this
// compilation unit (rule #19 — co-compiled kernels perturbed this kernel's
// codegen by ~5% in R7).
// A/B frag: [row=lane&31][k = kstep*16 + (lane>>5)*8 + j]
// C/D frag (m74/m101): col=lane&31, row=(reg&3)+8*(reg>>2)+4*(lane>>5)
// LDS XOR swizzle: LDS(row,c) holds global chunk c^(row&7) (16B chunks).
// MODE 0: fused QKV epilogue; Q scaled by 1/32 (folded logit scale).
// MODE 2: bf16 out, row-major ldc, z-strided   (logits, pre-scaled Q)
// MODE 3: fp32 out, row-major ldc, z-strided   (attn @ V^T)
// ============================================================================
template<int MODE>
__global__ __launch_bounds__(256)
void gemm_bt(const u16* __restrict__ Ain, const u16* __restrict__ Bin,
             void* __restrict__ Cv,
             const float* __restrict__ b0, const float* __restrict__ b1,
             const float* __restrict__ b2,
             int lda, int ldb, int ldc, int K,
             unsigned long long sA, unsigned long long sB, unsigned long long sC,
             int nbx, int nby)
{
  constexpr int BM = 128, BN = 128, BK = 64;
  __shared__ alignas(16) u16 As[BM * BK];
  __shared__ alignas(16) u16 Bs[BN * BK];

  // XCD-chunk + group-m swizzle
  const int nbxy = nbx * nby;
  const int bid  = blockIdx.x;
  const int flat = (bid & 7) * ((int)gridDim.x >> 3) + (bid >> 3);
  const int z    = flat / nbxy;
  const int rr   = flat - z * nbxy;
  const int width = nbx << 3;
  const int gid  = rr / width;
  const int rw   = rr - gid * width;
  const int by   = (gid << 3) + (rw & 7);
  const int bx   = rw >> 3;

  const u16* A = Ain + z * sA;
  const u16* B = Bin + z * sB;

  const int tid  = threadIdx.x;
  const int wave = tid >> 6;
  const int lane = tid & 63;
  const int l32  = lane & 31;
  const int half = lane >> 5;
  const int wr   = wave >> 1;     // 2x2 wave grid, 64x64 per wave
  const int wc   = wave & 1;

  const int m0 = by * BM;
  const int n0 = bx * BN;

  // staging: 64 lanes cover 8 rows x 8 chunks(16B) per instruction
  const int lr = lane >> 3;
  const int sc = ((lane & 7) ^ lr) * 8;     // swizzled global chunk
  const u16* Ag = A + (size_t)(m0 + wave * 32 + lr) * lda + sc;
  const u16* Bg = B + (size_t)(n0 + wave * 32 + lr) * ldb + sc;
  u16* Asb = &As[(wave * 32) * BK];
  u16* Bsb = &Bs[(wave * 32) * BK];

  f32x16 acc[2][2];
  #pragma unroll
  for (int i = 0; i < 2; ++i)
    #pragma unroll
    for (int j = 0; j < 2; ++j)
      #pragma unroll
      for (int r = 0; r < 16; ++r)
        acc[i][j][r] = 0.f;

  for (int k0 = 0; k0 < K; k0 += BK) {
    gload_lds16(Ag + k0,                    Asb);
    gload_lds16(Ag + (size_t) 8 * lda + k0, Asb +  8 * BK);
    gload_lds16(Ag + (size_t)16 * lda + k0, Asb + 16 * BK);
    gload_lds16(Ag + (size_t)24 * lda + k0, Asb + 24 * BK);
    gload_lds16(Bg + k0,                    Bsb);
    gload_lds16(Bg + (size_t) 8 * ldb + k0, Bsb +  8 * BK);
    gload_lds16(Bg + (size_t)16 * ldb + k0, Bsb + 16 * BK);
    gload_lds16(Bg + (size_t)24 * ldb + k0, Bsb + 24 * BK);
    __syncthreads();

    #pragma unroll
    for (int ks = 0; ks < 4; ++ks) {
      bf16x8 af[2], bfr[2];
      #pragma unroll
      for (int ti = 0; ti < 2; ++ti) {
        const int row = wr * 64 + ti * 32 + l32;
        const int ch  = ((ks * 2 + half) ^ (row & 7)) * 8;
        af[ti] = *(const bf16x8*)&As[row * BK + ch];
      }
      #pragma unroll
      for (int tj = 0; tj < 2; ++tj) {
        const int row = wc * 64 + tj * 32 + l32;
        const int ch  = ((ks * 2 + half) ^ (row & 7)) * 8;
        bfr[tj] = *(const bf16x8*)&Bs[row * BK + ch];
      }
      #pragma unroll
      for (int ti = 0; ti < 2; ++ti)
        #pragma unroll
        for (int tj = 0; tj < 2; ++tj)
          acc[ti][tj] = __builtin_amdgcn_mfma_f32_32x32x16_bf16(af[ti], bfr[tj], acc[ti][tj], 0, 0, 0);
    }
    __syncthreads();
  }

  // epilogue lane mapping
  const int colb = n0 + wc * 64 + l32;          // + tj*32
  const int rowb = m0 + wr * 64 + 4 * half;     // + ti*32 + (reg&3) + 8*(reg>>2)

  if constexpr (MODE == 0) {
    const int g = n0 >> 10;                     // 0=Q, 1=K, 2=V (block-uniform)
    u16* Qb = (u16*)Cv;
    if (g < 2) {
      u16* Cb = Qb + (size_t)g * 8388608ULL;
      const float* bp = (g == 0) ? b0 : b1;
      const float qs = (g == 0) ? 0.03125f : 1.0f;   // fold 1/sqrt(1024) into Q
      #pragma unroll
      for (int tj = 0; tj < 2; ++tj) {
        const int col = (colb + tj * 32) & 1023;
        const float bv = bp[col];
        #pragma unroll
        for (int ti = 0; ti < 2; ++ti)
          #pragma unroll
          for (int g4 = 0; g4 < 4; ++g4)
            #pragma unroll
            for (int r = 0; r < 4; ++r) {
              const int row = rowb + ti * 32 + g4 * 8 + r;
              Cb[(size_t)row * 1024 + col] = f2bf((acc[ti][tj][g4 * 4 + r] + bv) * qs);
            }
      }
    } else {
      u16* Vt = Qb + 16777216ULL;               // [4][1024][2048]
      #pragma unroll
      for (int tj = 0; tj < 2; ++tj) {
        const int col = (colb + tj * 32) & 1023;
        const float bv = b2[col];
        #pragma unroll
        for (int ti = 0; ti < 2; ++ti)
          #pragma unroll
          for (int g4 = 0; g4 < 4; ++g4) {
            const int row = rowb + ti * 32 + g4 * 8;   // 4 consecutive s
            u16x4 o;
            #pragma unroll
            for (int r = 0; r < 4; ++r) o[r] = f2bf(acc[ti][tj][g4 * 4 + r] + bv);
            const size_t idx = ((size_t)((row >> 11) * 1024 + col)) * 2048 + (row & 2047);
            *(u16x4*)&Vt[idx] = o;
          }
      }
    }
  } else if constexpr (MODE == 2) {
    u16* Cb = (u16*)Cv + z * sC;
    #pragma unroll
    for (int tj = 0; tj < 2; ++tj) {
      const int col = colb + tj * 32;
      #pragma unroll
      for (int ti = 0; ti < 2; ++ti)
        #pragma unroll
        for (int g4 = 0; g4 < 4; ++g4)
          #pragma unroll
          for (int r = 0; r < 4; ++r) {
            const int row = rowb + ti * 32 + g4 * 8 + r;
            Cb[(size_t)row * ldc + col] = f2bf(acc[ti][tj][g4 * 4 + r]);
          }
    }
  } else {
    float* Cf = (float*)Cv + z * sC;
    #pragma unroll
    for (int tj = 0; tj < 2; ++tj) {
      const int col = colb + tj * 32;
      #pragma unroll
      for (int ti = 0; ti < 2; ++ti)
        #pragma unroll
        for (int g4 = 0; g4 < 4; ++g4)
          #pragma unroll
          for (int r = 0; r < 4; ++r) {
            const int row = rowb + ti * 32 + g4 * 8 + r;
            Cf[(size_t)row * ldc + col] = acc[ti][tj][g4 * 4 + r];
          }
    }
  }
}

// one block per row; reads bf16 logits, writes fp32 attn to d_out and
// bf16 attn in-place (input to the PV gemm).
__global__ __launch_bounds__(256)
void softmax_rows(u16* __restrict__ logits, float* __restrict__ attn) {
  const int row = blockIdx.x;
  const int tid = threadIdx.x;
  u16*   lp = logits + (size_t)row * 2048 + tid * 8;
  float* ap = attn   + (size_t)row * 2048 + tid * 8;

  u16x8 raw = *(const u16x8*)lp;
  float v[8];
  #pragma unroll
  for (int j = 0; j < 8; ++j) v[j] = bf2f(raw[j]);

  float mx = v[0];
  #pragma unroll
  for (int j = 1; j < 8; ++j) mx = fmaxf(mx, v[j]);
  #pragma unroll
  for (int o = 32; o > 0; o >>= 1) mx = fmaxf(mx, __shfl_xor(mx, o, 64));

  __shared__ float smax[4], ssum[4];
  const int wv = tid >> 6, ln = tid & 63;
  if (ln == 0) smax[wv] = mx;
  __syncthreads();
  mx = fmaxf(fmaxf(smax[0], smax[1]), fmaxf(smax[2], smax[3]));

  float s = 0.f;
  #pragma unroll
  for (int j = 0; j < 8; ++j) { v[j] = __expf(v[j] - mx); s += v[j]; }
  #pragma unroll
  for (int o = 32; o > 0; o >>= 1) s += __shfl_xor(s, o, 64);
  if (ln == 0) ssum[wv] = s;
  __syncthreads();
  s = (ssum[0] + ssum[1]) + (ssum[2] + ssum[3]);
  const float inv = 1.f / s;

  u16x8 ob;
  #pragma unroll
  for (int j = 0; j < 8; ++j) { v[j] *= inv; ob[j] = f2bf(v[j]); }
  float4* apv = (float4*)ap;
  apv[0] = make_float4(v[0], v[1], v[2], v[3]);
  apv[1] = make_float4(v[4], v[5], v[6], v[7]);
  *(u16x8*)lp = ob;
}

extern "C" void kernel_launch(void* const* d_in, const int* in_sizes, int n_in,
                              void* d_out, int out_size, void* d_ws, size_t ws_size,
                              hipStream_t stream) {
  (void)in_sizes; (void)n_in; (void)out_size; (void)ws_size;
  const float* x    = (const float*)d_in[0];
  const float* wq_w = (const float*)d_in[1];
  const float* wq_b = (const float*)d_in[2];
  const float* wk_w = (const float*)d_in[3];
  const float* wk_b = (const float*)d_in[4];
  const float* wv_w = (const float*)d_in[5];
  const float* wv_b = (const float*)d_in[6];

  float* attn = (float*)d_out;                 // [4,2048,2048] fp32
  float* outp = attn + 16777216ULL;            // [4,2048,1024] fp32

  // ws layout (u16 elems): x_bf(8M) | wcat(3M) | Q(8M) | K(8M) | V^T(8M) | logits(16M)
  u16* xb   = (u16*)d_ws;
  u16* wcat = xb   + 8388608ULL;
  u16* Qb   = wcat + 3145728ULL;   // [8192][1024], pre-scaled by 1/32
  u16* Kb   = Qb   + 8388608ULL;   // [8192][1024]
  u16* Vt   = Kb   + 8388608ULL;   // [4][1024][2048]
  u16* Lg   = Vt   + 8388608ULL;   // [4][2048][2048]

  // fused conversions: one launch for x + all three weights
  cvt_all<<<11264, 256, 0, stream>>>(x, xb, wq_w, wk_w, wv_w, wcat);

  // fused QKV: M=8192, N=3072, K=1024
  gemm_bt<0><<<1536, 256, 0, stream>>>(xb, wcat, Qb, wq_b, wk_b, wv_b,
                                       1024, 1024, 1024, 1024, 0, 0, 0, 24, 64);

  // logits = (Q/32) K^T per batch: M=N=2048, K=1024
  gemm_bt<2><<<1024, 256, 0, stream>>>(Qb, Kb, Lg, nullptr, nullptr, nullptr,
                                       1024, 1024, 2048, 1024,
                                       2097152ULL, 2097152ULL, 4194304ULL, 16, 16);

  softmax_rows<<<8192, 256, 0, stream>>>(Lg, attn);

  // out = attn V: M=2048, N=1024, K=2048 per batch
  gemm_bt<3><<<512, 256, 0, stream>>>(Lg, Vt, outp, nullptr, nullptr, nullptr,
                                      2048, 2048, 1024, 2048,
                                      4194304ULL, 2097152ULL, 2097152ULL, 8, 16);
}

// Round 10
// 305.080 us; speedup vs baseline: 1.0976x; 1.0184x over previous
//
#include <hip/hip_runtime.h>

typedef unsigned short u16;
typedef u16 u16x4 __attribute__((ext_vector_type(4)));
typedef u16 u16x8 __attribute__((ext_vector_type(8)));
typedef __bf16 bf16x8 __attribute__((ext_vector_type(8)));
typedef float f32x16 __attribute__((ext_vector_type(16)));

static __device__ __forceinline__ u16 f2bf(float f) {
  unsigned u = __builtin_bit_cast(unsigned, f);
  u += 0x7fffu + ((u >> 16) & 1u);   // RNE; finite inputs
  return (u16)(u >> 16);
}
static __device__ __forceinline__ float bf2f(u16 h) {
  return __builtin_bit_cast(float, ((unsigned)h) << 16);
}

// async global->LDS, 16B/lane. LDS dest = wave-uniform base + lane*16.
static __device__ __forceinline__ void gload_lds16(const u16* g, u16* l) {
  u16* gn = const_cast<u16*>(g);
  __builtin_amdgcn_global_load_lds(
      (__attribute__((address_space(1))) unsigned int*)gn,
      (__attribute__((address_space(3))) unsigned int*)l,
      16, 0, 0);
}

// fused input conversions (R7/R8-validated): blocks [0,8192) convert x
// (fp32->bf16, 8M elems); blocks [8192,11264) convert the three weight
// matrices into wcat. One dispatch instead of two.
__global__ __launch_bounds__(256)
void cvt_all(const float* __restrict__ x, u16* __restrict__ xb,
             const float* __restrict__ a, const float* __restrict__ b,
             const float* __restrict__ c, u16* __restrict__ wcat) {
  const int blkid = blockIdx.x;
  if (blkid < 8192) {
    const int i = blkid * 256 + threadIdx.x;
    float4 f = ((const float4*)x)[i];
    u16x4 o = { f2bf(f.x), f2bf(f.y), f2bf(f.z), f2bf(f.w) };
    ((u16x4*)xb)[i] = o;
  } else {
    const int blk = blkid - 8192;     // 0..3071
    const int w = blk >> 10;
    const float* src = (w == 0) ? a : (w == 1) ? b : c;
    const int i = (blk & 1023) * 256 + threadIdx.x;
    float4 f = ((const float4*)src)[i];
    u16x4 o = { f2bf(f.x), f2bf(f.y), f2bf(f.z), f2bf(f.w) };
    ((u16x4*)(wcat + (size_t)w * 1048576ULL))[i] = o;
  }
}

// ============================================================================
// R0-proven 128x128 GEMM (best-measured artifact; golden — DO NOT TOUCH).
// C[m][n] = sum_k A[m][k]*B[n][k], k-contiguous. BM=BN=128, BK=64.
// mfma_f32_32x32x16_bf16; 4 waves (2x2), wave tile 64x64 = 2x2 of 32x32.
// Single-buffer: stage -> sync -> compute -> sync; 32 KiB LDS, VGPR 92 ->
// multi-block residency provides the cross-block overlap that hides the
// stage drain (m114). Single-variant build (rule #19): no other GEMM
// kernel in this compilation unit. Canary: VGPR_Count must stay 92.
// A/B frag: [row=lane&31][k = kstep*16 + (lane>>5)*8 + j]
// C/D frag (m74/m101): col=lane&31, row=(reg&3)+8*(reg>>2)+4*(lane>>5)
// LDS XOR swizzle: LDS(row,c) holds global chunk c^(row&7) (16B chunks).
// MODE 0: fused QKV epilogue; Q scaled by 1/32 (folded logit scale).
// MODE 2: bf16 out, row-major ldc, z-strided   (logits, pre-scaled Q)
// MODE 3: fp32 out, row-major ldc, z-strided   (attn @ V^T)
// ============================================================================
template<int MODE>
__global__ __launch_bounds__(256)
void gemm_bt(const u16* __restrict__ Ain, const u16* __restrict__ Bin,
             void* __restrict__ Cv,
             const float* __restrict__ b0, const float* __restrict__ b1,
             const float* __restrict__ b2,
             int lda, int ldb, int ldc, int K,
             unsigned long long sA, unsigned long long sB, unsigned long long sC,
             int nbx, int nby)
{
  constexpr int BM = 128, BN = 128, BK = 64;
  __shared__ alignas(16) u16 As[BM * BK];
  __shared__ alignas(16) u16 Bs[BN * BK];

  // XCD-chunk + group-m swizzle
  const int nbxy = nbx * nby;
  const int bid  = blockIdx.x;
  const int flat = (bid & 7) * ((int)gridDim.x >> 3) + (bid >> 3);
  const int z    = flat / nbxy;
  const int rr   = flat - z * nbxy;
  const int width = nbx << 3;
  const int gid  = rr / width;
  const int rw   = rr - gid * width;
  const int by   = (gid << 3) + (rw & 7);
  const int bx   = rw >> 3;

  const u16* A = Ain + z * sA;
  const u16* B = Bin + z * sB;

  const int tid  = threadIdx.x;
  const int wave = tid >> 6;
  const int lane = tid & 63;
  const int l32  = lane & 31;
  const int half = lane >> 5;
  const int wr   = wave >> 1;     // 2x2 wave grid, 64x64 per wave
  const int wc   = wave & 1;

  const int m0 = by * BM;
  const int n0 = bx * BN;

  // staging: 64 lanes cover 8 rows x 8 chunks(16B) per instruction
  const int lr = lane >> 3;
  const int sc = ((lane & 7) ^ lr) * 8;     // swizzled global chunk
  const u16* Ag = A + (size_t)(m0 + wave * 32 + lr) * lda + sc;
  const u16* Bg = B + (size_t)(n0 + wave * 32 + lr) * ldb + sc;
  u16* Asb = &As[(wave * 32) * BK];
  u16* Bsb = &Bs[(wave * 32) * BK];

  f32x16 acc[2][2];
  #pragma unroll
  for (int i = 0; i < 2; ++i)
    #pragma unroll
    for (int j = 0; j < 2; ++j)
      #pragma unroll
      for (int r = 0; r < 16; ++r)
        acc[i][j][r] = 0.f;

  for (int k0 = 0; k0 < K; k0 += BK) {
    gload_lds16(Ag + k0,                    Asb);
    gload_lds16(Ag + (size_t) 8 * lda + k0, Asb +  8 * BK);
    gload_lds16(Ag + (size_t)16 * lda + k0, Asb + 16 * BK);
    gload_lds16(Ag + (size_t)24 * lda + k0, Asb + 24 * BK);
    gload_lds16(Bg + k0,                    Bsb);
    gload_lds16(Bg + (size_t) 8 * ldb + k0, Bsb +  8 * BK);
    gload_lds16(Bg + (size_t)16 * ldb + k0, Bsb + 16 * BK);
    gload_lds16(Bg + (size_t)24 * ldb + k0, Bsb + 24 * BK);
    __syncthreads();

    #pragma unroll
    for (int ks = 0; ks < 4; ++ks) {
      bf16x8 af[2], bfr[2];
      #pragma unroll
      for (int ti = 0; ti < 2; ++ti) {
        const int row = wr * 64 + ti * 32 + l32;
        const int ch  = ((ks * 2 + half) ^ (row & 7)) * 8;
        af[ti] = *(const bf16x8*)&As[row * BK + ch];
      }
      #pragma unroll
      for (int tj = 0; tj < 2; ++tj) {
        const int row = wc * 64 + tj * 32 + l32;
        const int ch  = ((ks * 2 + half) ^ (row & 7)) * 8;
        bfr[tj] = *(const bf16x8*)&Bs[row * BK + ch];
      }
      #pragma unroll
      for (int ti = 0; ti < 2; ++ti)
        #pragma unroll
        for (int tj = 0; tj < 2; ++tj)
          acc[ti][tj] = __builtin_amdgcn_mfma_f32_32x32x16_bf16(af[ti], bfr[tj], acc[ti][tj], 0, 0, 0);
    }
    __syncthreads();
  }

  // epilogue lane mapping
  const int colb = n0 + wc * 64 + l32;          // + tj*32
  const int rowb = m0 + wr * 64 + 4 * half;     // + ti*32 + (reg&3) + 8*(reg>>2)

  if constexpr (MODE == 0) {
    const int g = n0 >> 10;                     // 0=Q, 1=K, 2=V (block-uniform)
    u16* Qb = (u16*)Cv;
    if (g < 2) {
      u16* Cb = Qb + (size_t)g * 8388608ULL;
      const float* bp = (g == 0) ? b0 : b1;
      const float qs = (g == 0) ? 0.03125f : 1.0f;   // fold 1/sqrt(1024) into Q
      #pragma unroll
      for (int tj = 0; tj < 2; ++tj) {
        const int col = (colb + tj * 32) & 1023;
        const float bv = bp[col];
        #pragma unroll
        for (int ti = 0; ti < 2; ++ti)
          #pragma unroll
          for (int g4 = 0; g4 < 4; ++g4)
            #pragma unroll
            for (int r = 0; r < 4; ++r) {
              const int row = rowb + ti * 32 + g4 * 8 + r;
              Cb[(size_t)row * 1024 + col] = f2bf((acc[ti][tj][g4 * 4 + r] + bv) * qs);
            }
      }
    } else {
      u16* Vt = Qb + 16777216ULL;               // [4][1024][2048]
      #pragma unroll
      for (int tj = 0; tj < 2; ++tj) {
        const int col = (colb + tj * 32) & 1023;
        const float bv = b2[col];
        #pragma unroll
        for (int ti = 0; ti < 2; ++ti)
          #pragma unroll
          for (int g4 = 0; g4 < 4; ++g4) {
            const int row = rowb + ti * 32 + g4 * 8;   // 4 consecutive s
            u16x4 o;
            #pragma unroll
            for (int r = 0; r < 4; ++r) o[r] = f2bf(acc[ti][tj][g4 * 4 + r] + bv);
            const size_t idx = ((size_t)((row >> 11) * 1024 + col)) * 2048 + (row & 2047);
            *(u16x4*)&Vt[idx] = o;
          }
      }
    }
  } else if constexpr (MODE == 2) {
    u16* Cb = (u16*)Cv + z * sC;
    #pragma unroll
    for (int tj = 0; tj < 2; ++tj) {
      const int col = colb + tj * 32;
      #pragma unroll
      for (int ti = 0; ti < 2; ++ti)
        #pragma unroll
        for (int g4 = 0; g4 < 4; ++g4)
          #pragma unroll
          for (int r = 0; r < 4; ++r) {
            const int row = rowb + ti * 32 + g4 * 8 + r;
            Cb[(size_t)row * ldc + col] = f2bf(acc[ti][tj][g4 * 4 + r]);
          }
    }
  } else {
    float* Cf = (float*)Cv + z * sC;
    #pragma unroll
    for (int tj = 0; tj < 2; ++tj) {
      const int col = colb + tj * 32;
      #pragma unroll
      for (int ti = 0; ti < 2; ++ti)
        #pragma unroll
        for (int g4 = 0; g4 < 4; ++g4)
          #pragma unroll
          for (int r = 0; r < 4; ++r) {
            const int row = rowb + ti * 32 + g4 * 8 + r;
            Cf[(size_t)row * ldc + col] = acc[ti][tj][g4 * 4 + r];
          }
    }
  }
}

// ============================================================================
// Barrier-free wave-per-row softmax (round-9 change, resubmitted after
// infra failure). One 64-lane wave owns a full 2048-elem row (32 elems/
// lane); max/sum reductions are pure __shfl_xor (6 steps) — ZERO
// __syncthreads, ZERO LDS. 4 rows per 256-thread block -> 2048 blocks
// (was 8192 blocks with a 2-level LDS reduction + 2 barriers). Same
// traffic, same coalescing (1 KiB per load instr per wave), fp32 accum.
// Reads bf16 logits; writes fp32 attn to d_out and bf16 attn in-place
// (input to the PV gemm).
// ============================================================================
__global__ __launch_bounds__(256)
void softmax_rows(u16* __restrict__ logits, float* __restrict__ attn) {
  const int wave = threadIdx.x >> 6;
  const int lane = threadIdx.x & 63;
  const int row  = blockIdx.x * 4 + wave;
  u16*   lp = logits + (size_t)row * 2048 + lane * 8;
  float* ap = attn   + (size_t)row * 2048 + lane * 8;

  float v[32];
  #pragma unroll
  for (int j = 0; j < 4; ++j) {
    u16x8 raw = *(const u16x8*)(lp + j * 512);
    #pragma unroll
    for (int e = 0; e < 8; ++e) v[j * 8 + e] = bf2f(raw[e]);
  }

  float mx = v[0];
  #pragma unroll
  for (int i = 1; i < 32; ++i) mx = fmaxf(mx, v[i]);
  #pragma unroll
  for (int o = 32; o > 0; o >>= 1) mx = fmaxf(mx, __shfl_xor(mx, o, 64));

  float s = 0.f;
  #pragma unroll
  for (int i = 0; i < 32; ++i) { v[i] = __expf(v[i] - mx); s += v[i]; }
  #pragma unroll
  for (int o = 32; o > 0; o >>= 1) s += __shfl_xor(s, o, 64);
  const float inv = 1.f / s;

  #pragma unroll
  for (int j = 0; j < 4; ++j) {
    u16x8 ob;
    #pragma unroll
    for (int e = 0; e < 8; ++e) {
      const float t = v[j * 8 + e] * inv;
      v[j * 8 + e] = t;
      ob[e] = f2bf(t);
    }
    float4* apv = (float4*)(ap + j * 512);
    apv[0] = make_float4(v[j * 8 + 0], v[j * 8 + 1], v[j * 8 + 2], v[j * 8 + 3]);
    apv[1] = make_float4(v[j * 8 + 4], v[j * 8 + 5], v[j * 8 + 6], v[j * 8 + 7]);
    *(u16x8*)(lp + j * 512) = ob;
  }
}

extern "C" void kernel_launch(void* const* d_in, const int* in_sizes, int n_in,
                              void* d_out, int out_size, void* d_ws, size_t ws_size,
                              hipStream_t stream) {
  (void)in_sizes; (void)n_in; (void)out_size; (void)ws_size;
  const float* x    = (const float*)d_in[0];
  const float* wq_w = (const float*)d_in[1];
  const float* wq_b = (const float*)d_in[2];
  const float* wk_w = (const float*)d_in[3];
  const float* wk_b = (const float*)d_in[4];
  const float* wv_w = (const float*)d_in[5];
  const float* wv_b = (const float*)d_in[6];

  float* attn = (float*)d_out;                 // [4,2048,2048] fp32
  float* outp = attn + 16777216ULL;            // [4,2048,1024] fp32

  // ws layout (u16 elems): x_bf(8M) | wcat(3M) | Q(8M) | K(8M) | V^T(8M) | logits(16M)
  u16* xb   = (u16*)d_ws;
  u16* wcat = xb   + 8388608ULL;
  u16* Qb   = wcat + 3145728ULL;   // [8192][1024], pre-scaled by 1/32
  u16* Kb   = Qb   + 8388608ULL;   // [8192][1024]
  u16* Vt   = Kb   + 8388608ULL;   // [4][1024][2048]
  u16* Lg   = Vt   + 8388608ULL;   // [4][2048][2048]

  // fused conversions: one launch for x + all three weights
  cvt_all<<<11264, 256, 0, stream>>>(x, xb, wq_w, wk_w, wv_w, wcat);

  // fused QKV: M=8192, N=3072, K=1024
  gemm_bt<0><<<1536, 256, 0, stream>>>(xb, wcat, Qb, wq_b, wk_b, wv_b,
                                       1024, 1024, 1024, 1024, 0, 0, 0, 24, 64);

  // logits = (Q/32) K^T per batch: M=N=2048, K=1024
  gemm_bt<2><<<1024, 256, 0, stream>>>(Qb, Kb, Lg, nullptr, nullptr, nullptr,
                                       1024, 1024, 2048, 1024,
                                       2097152ULL, 2097152ULL, 4194304ULL, 16, 16);

  // barrier-free wave-per-row softmax: 2048 blocks x 4 rows
  softmax_rows<<<2048, 256, 0, stream>>>(Lg, attn);

  // out = attn V: M=2048, N=1024, K=2048 per batch
  gemm_bt<3><<<512, 256, 0, stream>>>(Lg, Vt, outp, nullptr, nullptr, nullptr,
                                      2048, 2048, 1024, 2048,
                                      4194304ULL, 2097152ULL, 2097152ULL, 8, 16);
}